// Round 9
// baseline (448.791 us; speedup 1.0000x reference)
//
#include <hip/hip_runtime.h>
#include <math.h>

#define N0 32768
#define N1 8192
#define N2 2048
#define E0 262144
#define E1 65536
#define E2 16384
#define NTOT (N0+N1+N2)     // 43008
#define ETOT (E0+E1+E2)     // 344064
#define NBLK (NTOT/256)     // 168
#define EPS 1e-9f

static inline int cdiv(int a, int b){ return (a + b - 1) / b; }

__device__ inline unsigned bfpack(float a, float b){
  unsigned ua = __float_as_uint(a), ub = __float_as_uint(b);
  ua = (ua + 0x7fffu + ((ua >> 16) & 1u)) >> 16;
  ub = (ub + 0x7fffu + ((ub >> 16) & 1u)) & 0xffff0000u;
  return ua | ub;
}
__device__ inline float bf_lo(unsigned d){ return __uint_as_float(d << 16); }
__device__ inline float bf_hi(unsigned d){ return __uint_as_float(d & 0xffff0000u); }

// 32-lane-group full sum, DPP rotate-reduce (VALU) + one ds_swizzle xor16.
__device__ inline float grp32_sum(float x){
  x += __int_as_float(__builtin_amdgcn_update_dpp(0, __float_as_int(x), 0x121, 0xf, 0xf, true)); // ror:1
  x += __int_as_float(__builtin_amdgcn_update_dpp(0, __float_as_int(x), 0x122, 0xf, 0xf, true)); // ror:2
  x += __int_as_float(__builtin_amdgcn_update_dpp(0, __float_as_int(x), 0x124, 0xf, 0xf, true)); // ror:4
  x += __int_as_float(__builtin_amdgcn_update_dpp(0, __float_as_int(x), 0x128, 0xf, 0xf, true)); // ror:8
  x += __int_as_float(__builtin_amdgcn_ds_swizzle(__float_as_int(x), 0x401F));                   // xor:16
  return x;
}

// ---------------- small utility kernels ----------------
__global__ void k_gather_pos(const float* __restrict__ pos, const int* __restrict__ idx,
                             float* __restrict__ out, int n){
  int i = blockIdx.x*256 + threadIdx.x;
  if (i < n){
    int s = idx[i];
    out[i*3+0] = pos[s*3+0];
    out[i*3+1] = pos[s*3+1];
    out[i*3+2] = pos[s*3+2];
  }
}
__global__ void k_inv_build(const int* __restrict__ fp, int* __restrict__ inv, int n2){
  int i = blockIdx.x*256 + threadIdx.x;
  if (i < n2) inv[fp[i]] = i;
}

// ---------------- concatenated CSR build ----------------
__global__ void k_countA(const int* __restrict__ d0, const int* __restrict__ d1,
                         const int* __restrict__ d2, int* cnt){
  int e = blockIdx.x*256 + threadIdx.x;
  if (e < E0)            atomicAdd(&cnt[d0[e]], 1);
  else if (e < E0+E1)    atomicAdd(&cnt[N0 + d1[e-E0]], 1);
  else if (e < ETOT)     atomicAdd(&cnt[N0+N1 + d2[e-E0-E1]], 1);
}
__global__ __launch_bounds__(256) void k_scan1(const int* __restrict__ cnt,
                                               int* __restrict__ excl,
                                               int* __restrict__ bsum){
  __shared__ int lds[256];
  int tid = threadIdx.x;
  int i = blockIdx.x*256 + tid;
  int v = cnt[i];
  lds[tid] = v;
  __syncthreads();
  for (int off = 1; off < 256; off <<= 1){
    int t = (tid >= off) ? lds[tid - off] : 0;
    __syncthreads();
    lds[tid] += t;
    __syncthreads();
  }
  excl[i] = lds[tid] - v;
  if (tid == 255) bsum[blockIdx.x] = lds[255];
}
__global__ __launch_bounds__(256) void k_scan2(int* bsum, int nb){
  __shared__ int lds[256];
  int tid = threadIdx.x;
  int v = (tid < nb) ? bsum[tid] : 0;
  lds[tid] = v;
  __syncthreads();
  for (int off = 1; off < 256; off <<= 1){
    int t = (tid >= off) ? lds[tid - off] : 0;
    __syncthreads();
    lds[tid] += t;
    __syncthreads();
  }
  if (tid < nb) bsum[tid] = lds[tid] - v;
}
__global__ __launch_bounds__(256) void k_scan3(const int* __restrict__ excl,
                                               const int* __restrict__ bsum,
                                               int* __restrict__ row,
                                               int* __restrict__ cur){
  int i = blockIdx.x*256 + threadIdx.x;
  int r = excl[i] + bsum[blockIdx.x];
  row[i] = r; cur[i] = r;
  if (i == 0) row[NTOT] = ETOT;
}
__global__ void k_scatter_geoA(const int* __restrict__ s0, const int* __restrict__ d0,
                               const int* __restrict__ s1, const int* __restrict__ d1,
                               const int* __restrict__ s2, const int* __restrict__ d2,
                               const float* __restrict__ pos0, const float* __restrict__ pos1,
                               const float* __restrict__ pos2, int* cur,
                               int* __restrict__ srcs, float4* __restrict__ meta){
  int e = blockIdx.x*256 + threadIdx.x;
  if (e >= ETOT) return;
  int s, d, noff; const float* pos;
  if (e < E0)        { s = s0[e];        d = d0[e];        pos = pos0; noff = 0; }
  else if (e < E0+E1){ s = s1[e-E0];     d = d1[e-E0];     pos = pos1; noff = N0; }
  else               { s = s2[e-E0-E1];  d = d2[e-E0-E1];  pos = pos2; noff = N0+N1; }
  float dx = pos[d*3+0]-pos[s*3+0];
  float dy = pos[d*3+1]-pos[s*3+1];
  float dz = pos[d*3+2]-pos[s*3+2];
  int p = atomicAdd(&cur[noff + d], 1);
  srcs[p] = s;
  meta[p] = make_float4(sqrtf(dx*dx+dy*dy+dz*dz+1e-12f), dx, dy, dz);
}

// ---------------- layer-9 radial bias precompute (for the head loop) ----
__global__ __launch_bounds__(256) void k_rbias(const float4* __restrict__ meta,
                                               const float* __restrict__ w1,
                                               const float* __restrict__ w2,
                                               float* __restrict__ rb, int nE){
  int e = blockIdx.x*256 + threadIdx.x;
  if (e >= nE) return;
  float r = meta[e].x;
  float a = 0.f;
  #pragma unroll
  for (int j = 0; j < 16; ++j) a += fmaxf(r*w1[j], 0.f)*w2[j];
  rb[e] = a;
}

// ---------------- transform: q, packed-kv (bf16), skip (Cout=32) ----------------
// mode 0: x plain | mode 1: POOL x=sum/(cnt+EPS) | mode 2: UPS x=base+up[inv]
__global__ __launch_bounds__(256) void k_transformF(
    const float* __restrict__ x, const float* __restrict__ cntv,
    const float* __restrict__ up, const int* __restrict__ inv,
    const float* __restrict__ Wq, const float* __restrict__ Wk,
    const float* __restrict__ Wv, const float* __restrict__ Ws,
    float* __restrict__ q, unsigned* __restrict__ kv, float* __restrict__ s,
    int n, int Cin, int mode){
  __shared__ float wI[4096];
  __shared__ float xr4[8][128];
  __shared__ float kvst[8][192];
  int tid = threadIdx.x;
  int nw = Cin * 32;
  for (int i = tid; i < nw; i += 256){
    wI[i*4+0] = Wq[i]; wI[i*4+1] = Wk[i]; wI[i*4+2] = Wv[i]; wI[i*4+3] = Ws[i];
  }
  int g = tid >> 5, lane = tid & 31;
  int node = blockIdx.x*8 + g;
  int xl = Cin * 3;
  if (node < n){
    if (mode == 1){
      float ic = 1.f / (cntv[node] + EPS);
      for (int c = lane; c < Cin; c += 32){
        int b = node*xl + c*3;
        xr4[g][c*4+0] = x[b+0]*ic; xr4[g][c*4+1] = x[b+1]*ic; xr4[g][c*4+2] = x[b+2]*ic;
      }
    } else if (mode == 2){
      int a = inv[node];
      for (int c = lane; c < Cin; c += 32){
        int b = node*xl + c*3;
        float v0_ = x[b], v1_ = x[b+1], v2_ = x[b+2];
        if (a >= 0){
          size_t ub = (size_t)a*xl + c*3;
          v0_ += up[ub]; v1_ += up[ub+1]; v2_ += up[ub+2];
        }
        xr4[g][c*4+0] = v0_; xr4[g][c*4+1] = v1_; xr4[g][c*4+2] = v2_;
      }
    } else {
      for (int c = lane; c < Cin; c += 32){
        int b = node*xl + c*3;
        xr4[g][c*4+0] = x[b]; xr4[g][c*4+1] = x[b+1]; xr4[g][c*4+2] = x[b+2];
      }
    }
  }
  __syncthreads();
  if (node < n){
    float aq0=0.f,aq1=0.f,aq2=0.f, ak0=0.f,ak1=0.f,ak2=0.f;
    float aw0=0.f,aw1=0.f,aw2=0.f, as0=0.f,as1=0.f,as2=0.f;
    for (int c = 0; c < Cin; ++c){
      float4 xv = *(const float4*)&xr4[g][c*4];
      float4 wv = *(const float4*)&wI[(c*32+lane)*4];
      aq0 += xv.x*wv.x; aq1 += xv.y*wv.x; aq2 += xv.z*wv.x;
      ak0 += xv.x*wv.y; ak1 += xv.y*wv.y; ak2 += xv.z*wv.y;
      aw0 += xv.x*wv.z; aw1 += xv.y*wv.z; aw2 += xv.z*wv.z;
      as0 += xv.x*wv.w; as1 += xv.y*wv.w; as2 += xv.z*wv.w;
    }
    int o = node*96 + lane*3;
    q[o]=aq0; q[o+1]=aq1; q[o+2]=aq2;
    s[o]=as0; s[o+1]=as1; s[o+2]=as2;
    kvst[g][lane*3+0]=ak0; kvst[g][lane*3+1]=ak1; kvst[g][lane*3+2]=ak2;
    kvst[g][96+lane*3+0]=aw0; kvst[g][96+lane*3+1]=aw1; kvst[g][96+lane*3+2]=aw2;
    float2 p0 = *(const float2*)&kvst[g][2*lane];
    float2 p1 = *(const float2*)&kvst[g][64+2*lane];
    float2 p2 = *(const float2*)&kvst[g][128+2*lane];
    *(uint2*)(kv + (size_t)node*96 + 2*lane) = make_uint2(bfpack(p0.x,p0.y), bfpack(p1.x,p1.y));
    kv[(size_t)node*96 + 64 + lane] = bfpack(p2.x, p2.y);
  }
}

// ---------------- attention core (8-wide edge batch, DPP reduce, uint2 KV) ----------------
// 8 edges' gathers (16 loads/lane) issue in ONE latency window per typical
// node (avg degree 8) vs two windows at width 4. Straight-line unroll — no
// copies/branches (the R4 pipeline's overhead). Register cost ~+16 VGPR,
// capped below the 64-VGPR occupancy cliff by __launch_bounds__(256,8).
#define ATTN_CORE(QB,KVB,SB) \
  float rw1 = (lane < 16) ? wr1[lane] : 0.f; \
  float rw2 = (lane < 16) ? wr2[lane] : 0.f; \
  float ql0=0.f, ql1=0.f, ql2=0.f, ql3=0.f; \
  float z=0.f, av0=0.f, av1=0.f, av2=0.f, av3=0.f, R0=0.f, R1=0.f, R2=0.f; \
  int beg=0, end=0; \
  if (act){ \
    int nb = node*96; \
    float2 qa = *(const float2*)(QB + nb + 2*lane); \
    ql0 = qa.x*invsc; ql1 = qa.y*invsc; \
    if (lane < 16){ \
      float2 qc = *(const float2*)(QB + nb + 64 + 2*lane); \
      ql2 = qc.x*invsc; ql3 = qc.y*invsc; \
    } \
    beg = row[node]; end = row[node+1]; \
  } \
  for (int cb = beg; cb < end; cb += 32){ \
    int csz = end - cb; if (csz > 32) csz = 32; \
    int sn_l = 0; float4 mt = make_float4(0.f,0.f,0.f,0.f); \
    if (lane < csz){ \
      int idx = cb + lane; \
      sn_l = srcs[idx]; \
      mt = meta[idx]; \
    } \
    for (int j = 0; j < csz; j += 8){ \
      int gs = csz - j; if (gs > 8) gs = 8; \
      unsigned d0[8], d1[8], d2[8]; float rr[8]; \
      _Pragma("unroll") \
      for (int t = 0; t < 8; ++t){ \
        int sl = (j + t) & 31; \
        int sid = __shfl(sn_l, sl, 32); \
        rr[t] = __shfl(mt.x, sl, 32); \
        const unsigned* kp = KVB + (size_t)sid*96; \
        bool ok = t < gs; \
        uint2 ab = ok ? *(const uint2*)(kp + 2*lane) : make_uint2(0u,0u); \
        d0[t] = ab.x; d1[t] = ab.y; \
        d2[t] = ok ? kp[64 + lane] : 0u; \
      } \
      _Pragma("unroll") \
      for (int t = 0; t < 8; ++t){ \
        float pt = bf_lo(d0[t])*ql0 + bf_hi(d0[t])*ql1; \
        if (lane < 16) pt += bf_lo(d1[t])*ql2 + bf_hi(d1[t])*ql3; \
        pt += fmaxf(rr[t]*rw1, 0.f) * rw2; \
        pt = grp32_sum(pt); \
        float w = (t < gs) ? __expf(fminf(pt, 80.f)) : 0.f; \
        z += w; \
        av0 += w*bf_lo(d2[t]); av1 += w*bf_hi(d2[t]); \
        if (lane >= 16){ av2 += w*bf_lo(d1[t]); av3 += w*bf_hi(d1[t]); } \
        if (lane == j + t){ R0 += w*mt.y; R1 += w*mt.z; R2 += w*mt.w; } \
      } \
    } \
  } \
  R0 = grp32_sum(R0); \
  R1 = grp32_sum(R1); \
  R2 = grp32_sum(R2); \
  if (act){ \
    vsum[g][2*lane+32] = av0; \
    vsum[g][2*lane+33] = av1; \
    if (lane >= 16){ vsum[g][2*lane-32] = av2; vsum[g][2*lane-31] = av3; } \
  } \
  float y0=0.f, y1=0.f, y2=0.f; \
  if (act){ \
    float invz = 1.f / (z + EPS); \
    int base = node*96 + 3*lane; \
    y0 = (vsum[g][3*lane+0] + R0)*invz + SB[base]; \
    y1 = (vsum[g][3*lane+1] + R1)*invz + SB[base+1]; \
    y2 = (vsum[g][3*lane+2] + R2)*invz + SB[base+2]; \
    float nrm = sqrtf(y0*y0 + y1*y1 + y2*y2 + 1e-12f); \
    float f = fmaxf(scaleA[lane]*nrm + biasA[lane], 0.f) / nrm; \
    y0 *= f; y1 *= f; y2 *= f; \
  }

// ---------------- plain attention (odd layers): writes y, optional fused pool ----------------
__global__ __launch_bounds__(256, 8) void k_attn32(
    const float* __restrict__ qb, const unsigned* __restrict__ kvb,
    const float* __restrict__ sb,
    const int* __restrict__ row, const int* __restrict__ srcs,
    const float4* __restrict__ meta,
    const float* __restrict__ wr1, const float* __restrict__ wr2,
    const float* __restrict__ scaleA, const float* __restrict__ biasA,
    float* __restrict__ outb,
    float* psum, float* pcnt_, const int* __restrict__ cl,
    int n, float invsc){
  __shared__ float vsum[8][96];
  int tid = threadIdx.x, g = tid >> 5, lane = tid & 31;
  int node = blockIdx.x*8 + g;
  bool act = node < n;
  ATTN_CORE(qb, kvb, sb)
  if (act){
    int base = node*96 + 3*lane;
    outb[base]   = y0;
    outb[base+1] = y1;
    outb[base+2] = y2;
    if (cl){                        // fused segment-sum pooling
      int c = cl[node];
      atomicAdd(&psum[c*96 + 3*lane],   y0);
      atomicAdd(&psum[c*96 + 3*lane+1], y1);
      atomicAdd(&psum[c*96 + 3*lane+2], y2);
      if (lane == 0) atomicAdd(&pcnt_[c], 1.f);
    }
  }
}

// ---------------- fused attention + next-layer transform (Cout=32) ----------------
__global__ __launch_bounds__(256, 8) void k_attn32_t32(
    float* __restrict__ qb, const unsigned* __restrict__ kvin,
    float* __restrict__ sb,
    const int* __restrict__ row, const int* __restrict__ srcs,
    const float4* __restrict__ meta,
    const float* __restrict__ wr1, const float* __restrict__ wr2,
    const float* __restrict__ scaleA, const float* __restrict__ biasA,
    const float* __restrict__ Wq2, const float* __restrict__ Wk2,
    const float* __restrict__ Wv2, const float* __restrict__ Ws2,
    unsigned* __restrict__ kvout, int n, float invsc){
  __shared__ float vsum[8][96];
  __shared__ float wI[4096];
  __shared__ float kvst[8][192];
  int tid = threadIdx.x, g = tid >> 5, lane = tid & 31;
  for (int i = tid; i < 1024; i += 256){
    wI[i*4+0] = Wq2[i]; wI[i*4+1] = Wk2[i]; wI[i*4+2] = Wv2[i]; wI[i*4+3] = Ws2[i];
  }
  int node = blockIdx.x*8 + g;
  bool act = node < n;
  ATTN_CORE(qb, kvin, sb)
  __syncthreads();
  if (act){
    vsum[g][3*lane+0] = y0;
    vsum[g][3*lane+1] = y1;
    vsum[g][3*lane+2] = y2;
    float aq0=0.f,aq1=0.f,aq2=0.f, ak0=0.f,ak1=0.f,ak2=0.f;
    float aw0=0.f,aw1=0.f,aw2=0.f, as0=0.f,as1=0.f,as2=0.f;
    for (int c = 0; c < 32; ++c){
      float x0 = vsum[g][c*3+0], x1 = vsum[g][c*3+1], x2 = vsum[g][c*3+2];
      float4 wv = *(const float4*)&wI[(c*32+lane)*4];
      aq0 += x0*wv.x;  aq1 += x1*wv.x;  aq2 += x2*wv.x;
      ak0 += x0*wv.y;  ak1 += x1*wv.y;  ak2 += x2*wv.y;
      aw0 += x0*wv.z;  aw1 += x1*wv.z;  aw2 += x2*wv.z;
      as0 += x0*wv.w;  as1 += x1*wv.w;  as2 += x2*wv.w;
    }
    int ob = node*96 + 3*lane;
    qb[ob]=aq0; qb[ob+1]=aq1; qb[ob+2]=aq2;
    sb[ob]=as0; sb[ob+1]=as1; sb[ob+2]=as2;
    kvst[g][lane*3+0]=ak0; kvst[g][lane*3+1]=ak1; kvst[g][lane*3+2]=ak2;
    kvst[g][96+lane*3+0]=aw0; kvst[g][96+lane*3+1]=aw1; kvst[g][96+lane*3+2]=aw2;
    float2 p0 = *(const float2*)&kvst[g][2*lane];
    float2 p1 = *(const float2*)&kvst[g][64+2*lane];
    float2 p2 = *(const float2*)&kvst[g][128+2*lane];
    *(uint2*)(kvout + (size_t)node*96 + 2*lane) = make_uint2(bfpack(p0.x,p0.y), bfpack(p1.x,p1.y));
    kvout[(size_t)node*96 + 64 + lane] = bfpack(p2.x, p2.y);
  }
}

// ---------------- fused attention + Cout=1 transform (pair 8,9) ----------------
__global__ __launch_bounds__(256, 8) void k_attn32_t1(
    const float* __restrict__ qb, const unsigned* __restrict__ kvin,
    const float* __restrict__ sb,
    const int* __restrict__ row, const int* __restrict__ srcs,
    const float4* __restrict__ meta,
    const float* __restrict__ wr1, const float* __restrict__ wr2,
    const float* __restrict__ scaleA, const float* __restrict__ biasA,
    const float* __restrict__ Wq2, const float* __restrict__ Wk2,
    const float* __restrict__ Wv2, const float* __restrict__ Ws2,
    float* __restrict__ q1, float* __restrict__ kv1,
    float* __restrict__ s1,
    int n, float invsc){
  __shared__ float vsum[8][96];
  int tid = threadIdx.x, g = tid >> 5, lane = tid & 31;
  int node = blockIdx.x*8 + g;
  bool act = node < n;
  ATTN_CORE(qb, kvin, sb)
  if (act){
    vsum[g][3*lane+0] = y0;
    vsum[g][3*lane+1] = y1;
    vsum[g][3*lane+2] = y2;
  }
  if (act && lane < 12){
    int m = lane / 3, v = lane - m*3;
    const float* W = (m==0) ? Wq2 : (m==1) ? Wk2 : (m==2) ? Wv2 : Ws2;
    float a = 0.f;
    for (int c = 0; c < 32; ++c) a += vsum[g][c*3+v] * W[c];
    if (m==0)      q1[node*3 + v] = a;
    else if (m==1) kv1[(size_t)node*8 + v] = a;       // k at [0..2]
    else if (m==2) kv1[(size_t)node*8 + 3 + v] = a;   // v at [3..5]
    else           s1[node*3 + v] = a;
  }
}

// ---------------- Cout=1 attention fused with MLP head (8 lanes/node) ----------------
__global__ __launch_bounds__(256) void k_attn1_head(
    const float* __restrict__ qb, const float* __restrict__ kv1,
    const float* __restrict__ sb, const float* __restrict__ rb9,
    const int* __restrict__ row, const int* __restrict__ srcs,
    const float4* __restrict__ meta,
    const float* __restrict__ scaleA, const float* __restrict__ biasA,
    const float* __restrict__ Wmlp,
    float* __restrict__ out, int n, float invsc){
  __shared__ float w[120];
  int tid = threadIdx.x;
  if (tid < 120) w[tid] = Wmlp[tid];
  __syncthreads();
  int i = blockIdx.x*32 + (tid >> 3);   // 32 nodes per block, 8 lanes each
  int lane8 = tid & 7;
  if (i >= n) return;
  float q0 = qb[i*3]*invsc, q1 = qb[i*3+1]*invsc, q2 = qb[i*3+2]*invsc;
  float z = 0.f, a0 = 0.f, a1 = 0.f, a2 = 0.f;
  int beg = row[i], end = row[i+1];
  for (int e = beg + lane8; e < end; e += 8){
    int s = srcs[e];
    float4 m = meta[e];
    float4 A = *(const float4*)(kv1 + (size_t)s*8);      // k0,k1,k2,v0
    float2 B = *(const float2*)(kv1 + (size_t)s*8 + 4);  // v1,v2
    float pt = q0*A.x + q1*A.y + q2*A.z + rb9[e];
    float wgt = __expf(fminf(pt, 80.f));
    z += wgt;
    a0 += wgt*(A.w + m.y); a1 += wgt*(B.x + m.z); a2 += wgt*(B.y + m.w);
  }
  // butterfly reduce across the 8 lanes of this node
  #pragma unroll
  for (int xm = 1; xm <= 4; xm <<= 1){
    z  += __shfl_xor(z,  xm, 8);
    a0 += __shfl_xor(a0, xm, 8);
    a1 += __shfl_xor(a1, xm, 8);
    a2 += __shfl_xor(a2, xm, 8);
  }
  float invz = 1.f / (z + EPS);
  float y0 = a0*invz + sb[i*3];
  float y1 = a1*invz + sb[i*3+1];
  float y2 = a2*invz + sb[i*3+2];
  float nrm = sqrtf(y0*y0 + y1*y1 + y2*y2 + 1e-12f);
  float f = fmaxf(scaleA[0]*nrm + biasA[0], 0.f) / nrm;
  y0 *= f; y1 *= f; y2 *= f;
  #pragma unroll
  for (int c = 0; c < 5; ++c){
    int o2 = lane8*5 + c;
    out[(size_t)i*40 + o2] = fmaxf(y0*w[o2] + y1*w[40+o2] + y2*w[80+o2], 0.f);
  }
}

extern "C" void kernel_launch(void* const* d_in, const int* in_sizes, int n_in,
                              void* d_out, int out_size, void* d_ws, size_t ws_size,
                              hipStream_t stream){
  const float* pos0      = (const float*)d_in[0];
  const float* v0        = (const float*)d_in[1];
  const float* Wq_first  = (const float*)d_in[2];
  const float* Wk_first  = (const float*)d_in[3];
  const float* Wv_first  = (const float*)d_in[4];
  const float* Ws_first  = (const float*)d_in[5];
  const float* Wq_mid    = (const float*)d_in[6];
  const float* Wk_mid    = (const float*)d_in[7];
  const float* Wv_mid    = (const float*)d_in[8];
  const float* Ws_mid    = (const float*)d_in[9];
  const float* Wq_last   = (const float*)d_in[10];
  const float* Wk_last   = (const float*)d_in[11];
  const float* Wv_last   = (const float*)d_in[12];
  const float* Ws_last   = (const float*)d_in[13];
  const float* wr1       = (const float*)d_in[14];
  const float* wr2       = (const float*)d_in[15];
  const float* scale_mid = (const float*)d_in[16];
  const float* bias_mid  = (const float*)d_in[17];
  const float* scale_last= (const float*)d_in[18];
  const float* bias_last = (const float*)d_in[19];
  const float* Wmlp      = (const float*)d_in[20];
  const int* src0 = (const int*)d_in[21];
  const int* dst0 = (const int*)d_in[22];
  const int* src1 = (const int*)d_in[23];
  const int* dst1 = (const int*)d_in[24];
  const int* src2 = (const int*)d_in[25];
  const int* dst2 = (const int*)d_in[26];
  const int* fp1  = (const int*)d_in[27];
  const int* fp2  = (const int*)d_in[28];
  const int* cl1  = (const int*)d_in[29];
  const int* cl2  = (const int*)d_in[30];

  float* ws = (float*)d_ws;
  size_t o = 0;
  float* xA   = ws + o; o += (size_t)N0*96;   // scratch fiber (attn5/attn7 outputs)
  float* x0s  = ws + o; o += (size_t)N0*96;   // level-0 skip
  float* x1s  = ws + o; o += (size_t)N1*96;   // level-1 skip
  float* xP1  = ws + o; o += (size_t)N1*96;   // pool-1 sums
  float* xP2  = ws + o; o += (size_t)N2*96;   // pool-2 sums
  float* qb   = ws + o; o += (size_t)N0*96;
  float* sb   = ws + o; o += (size_t)N0*96;
  unsigned* kvb  = (unsigned*)(ws + o); o += (size_t)N0*96;
  unsigned* kvb2 = (unsigned*)(ws + o); o += (size_t)N0*96;
  float4* metaA = (float4*)(ws + o); o += (size_t)ETOT*4;
  float* q1v  = ws + o; o += (size_t)N0*3;
  float* s1v  = ws + o; o += (size_t)N0*3;
  float* kv1  = ws + o; o += (size_t)N0*8;    // packed k(3),v(3),pad(2)
  float* rb9  = ws + o; o += (size_t)E0;      // layer-9 radial bias per level-0 edge
  float* pcnt1 = ws + o; o += N1;
  float* pcnt2 = ws + o; o += N2;
  float* pos1 = ws + o; o += (size_t)N1*3;
  float* pos2 = ws + o; o += (size_t)N2*3;
  int* ib = (int*)(ws + o);
  size_t io = 0;
  int* rowA  = ib + io; io += NTOT+1;
  int* cntA  = ib + io; io += NTOT;
  int* curA  = ib + io; io += NTOT;
  int* exclA = ib + io; io += NTOT;
  int* bsumA = ib + io; io += 256;
  int* srcsA = ib + io; io += ETOT;
  int* inv0  = ib + io; io += N0;
  int* inv1  = ib + io; io += N1;

  // ---- zero pool accumulators up-front (graph-safe, before any attn writes) ----
  hipMemsetAsync(xP1, 0, (size_t)N1*96*sizeof(float), stream);
  hipMemsetAsync(xP2, 0, (size_t)N2*96*sizeof(float), stream);
  hipMemsetAsync(pcnt1, 0, N1*sizeof(float), stream);
  hipMemsetAsync(pcnt2, 0, N2*sizeof(float), stream);
  hipMemsetAsync(inv0, 0xFF, N0*sizeof(int), stream);
  hipMemsetAsync(inv1, 0xFF, N1*sizeof(int), stream);
  hipMemsetAsync(cntA, 0, NTOT*sizeof(int), stream);

  k_gather_pos<<<cdiv(N1,256),256,0,stream>>>(pos0, fp1, pos1, N1);
  k_gather_pos<<<cdiv(N2,256),256,0,stream>>>(pos1, fp2, pos2, N2);
  k_inv_build<<<cdiv(N1,256),256,0,stream>>>(fp1, inv0, N1);
  k_inv_build<<<cdiv(N2,256),256,0,stream>>>(fp2, inv1, N2);

  k_countA<<<cdiv(ETOT,256),256,0,stream>>>(dst0, dst1, dst2, cntA);
  k_scan1<<<NBLK,256,0,stream>>>(cntA, exclA, bsumA);
  k_scan2<<<1,256,0,stream>>>(bsumA, NBLK);
  k_scan3<<<NBLK,256,0,stream>>>(exclA, bsumA, rowA, curA);
  k_scatter_geoA<<<cdiv(ETOT,256),256,0,stream>>>(src0, dst0, src1, dst1, src2, dst2,
                                                  pos0, pos1, pos2, curA, srcsA, metaA);
  k_rbias<<<cdiv(E0,256),256,0,stream>>>(metaA, wr1 + 9*16, wr2 + 9*16, rb9, E0);

  const float invsc = 1.f / sqrtf(96.f);
  const int C = 32;

  // pair driver: T_even(mode), attn_even+T_odd, attn_odd(+pool)
  auto pair32 = [&](const float* xin, const float* cntv, const float* up, const int* inv,
                    int mode, int n, int nodeBase, int Cin,
                    const float* WqE, const float* WkE, const float* WvE, const float* WsE,
                    const float* WqO, const float* WkO, const float* WvO, const float* WsO,
                    int lE, float* xout,
                    float* psum, float* pcnt_, const int* cl){
    k_transformF<<<cdiv(n,8),256,0,stream>>>(xin, cntv, up, inv, WqE, WkE, WvE, WsE,
                                             qb, kvb, sb, n, Cin, mode);
    k_attn32_t32<<<cdiv(n,8),256,0,stream>>>(qb, kvb, sb, rowA + nodeBase, srcsA, metaA,
                                             wr1 + lE*16, wr2 + lE*16,
                                             scale_mid + lE*C, bias_mid + lE*C,
                                             WqO, WkO, WvO, WsO, kvb2, n, invsc);
    k_attn32<<<cdiv(n,8),256,0,stream>>>(qb, kvb2, sb, rowA + nodeBase, srcsA, metaA,
                                         wr1 + (lE+1)*16, wr2 + (lE+1)*16,
                                         scale_mid + (lE+1)*C, bias_mid + (lE+1)*C,
                                         xout, psum, pcnt_, cl, n, invsc);
  };

  // pair (0,1) level 0 -> x0s, fused pool into xP1/pcnt1
  pair32(v0, nullptr, nullptr, nullptr, 0, N0, 0, 1,
         Wq_first, Wk_first, Wv_first, Ws_first,
         Wq_mid+0*1024, Wk_mid+0*1024, Wv_mid+0*1024, Ws_mid+0*1024,
         0, x0s, xP1, pcnt1, cl1);
  // pair (2,3) level 1 (POOL input) -> x1s, fused pool into xP2/pcnt2
  pair32(xP1, pcnt1, nullptr, nullptr, 1, N1, N0, C,
         Wq_mid+1*1024, Wk_mid+1*1024, Wv_mid+1*1024, Ws_mid+1*1024,
         Wq_mid+2*1024, Wk_mid+2*1024, Wv_mid+2*1024, Ws_mid+2*1024,
         2, x1s, xP2, pcnt2, cl2);
  // pair (4,5) level 2 (POOL input) -> xA (N2 rows)
  pair32(xP2, pcnt2, nullptr, nullptr, 1, N2, N0+N1, C,
         Wq_mid+3*1024, Wk_mid+3*1024, Wv_mid+3*1024, Ws_mid+3*1024,
         Wq_mid+4*1024, Wk_mid+4*1024, Wv_mid+4*1024, Ws_mid+4*1024,
         4, xA, nullptr, nullptr, nullptr);
  // pair (6,7) level 1 (UPS input: x1s + xA[inv1]) -> xA (N1 rows)
  pair32(x1s, nullptr, xA, inv1, 2, N1, N0, C,
         Wq_mid+5*1024, Wk_mid+5*1024, Wv_mid+5*1024, Ws_mid+5*1024,
         Wq_mid+6*1024, Wk_mid+6*1024, Wv_mid+6*1024, Ws_mid+6*1024,
         6, xA, nullptr, nullptr, nullptr);
  // pair (8,9): T8 (UPS input: x0s + xA[inv0]), attn8+T9(Cout=1), attn9+head
  k_transformF<<<cdiv(N0,8),256,0,stream>>>(x0s, nullptr, xA, inv0,
                                            Wq_mid+7*1024, Wk_mid+7*1024,
                                            Wv_mid+7*1024, Ws_mid+7*1024,
                                            qb, kvb, sb, N0, C, 2);
  k_attn32_t1<<<cdiv(N0,8),256,0,stream>>>(qb, kvb, sb, rowA, srcsA, metaA,
                                           wr1 + 8*16, wr2 + 8*16,
                                           scale_mid + 8*C, bias_mid + 8*C,
                                           Wq_last, Wk_last, Wv_last, Ws_last,
                                           q1v, kv1, s1v, N0, invsc);
  {
    float invsc1 = 1.f / sqrtf(3.f);
    k_attn1_head<<<cdiv(N0,32),256,0,stream>>>(q1v, kv1, s1v, rb9, rowA, srcsA, metaA,
                                               scale_last, bias_last,
                                               Wmlp, (float*)d_out, N0, invsc1);
  }
}

// Round 10
// 432.958 us; speedup vs baseline: 1.0366x; 1.0366x over previous
//
#include <hip/hip_runtime.h>
#include <math.h>

#define N0 32768
#define N1 8192
#define N2 2048
#define E0 262144
#define E1 65536
#define E2 16384
#define NTOT (N0+N1+N2)     // 43008
#define ETOT (E0+E1+E2)     // 344064
#define NBLK (NTOT/256)     // 168
#define EPS 1e-9f

static inline int cdiv(int a, int b){ return (a + b - 1) / b; }

__device__ inline unsigned bfpack(float a, float b){
  unsigned ua = __float_as_uint(a), ub = __float_as_uint(b);
  ua = (ua + 0x7fffu + ((ua >> 16) & 1u)) >> 16;
  ub = (ub + 0x7fffu + ((ub >> 16) & 1u)) & 0xffff0000u;
  return ua | ub;
}
__device__ inline float bf_lo(unsigned d){ return __uint_as_float(d << 16); }
__device__ inline float bf_hi(unsigned d){ return __uint_as_float(d & 0xffff0000u); }

// 32-lane-group full sum, DPP rotate-reduce (VALU) + one ds_swizzle xor16.
__device__ inline float grp32_sum(float x){
  x += __int_as_float(__builtin_amdgcn_update_dpp(0, __float_as_int(x), 0x121, 0xf, 0xf, true)); // ror:1
  x += __int_as_float(__builtin_amdgcn_update_dpp(0, __float_as_int(x), 0x122, 0xf, 0xf, true)); // ror:2
  x += __int_as_float(__builtin_amdgcn_update_dpp(0, __float_as_int(x), 0x124, 0xf, 0xf, true)); // ror:4
  x += __int_as_float(__builtin_amdgcn_update_dpp(0, __float_as_int(x), 0x128, 0xf, 0xf, true)); // ror:8
  x += __int_as_float(__builtin_amdgcn_ds_swizzle(__float_as_int(x), 0x401F));                   // xor:16
  return x;
}

// ---------------- small utility kernels ----------------
__global__ void k_gather_pos(const float* __restrict__ pos, const int* __restrict__ idx,
                             float* __restrict__ out, int n){
  int i = blockIdx.x*256 + threadIdx.x;
  if (i < n){
    int s = idx[i];
    out[i*3+0] = pos[s*3+0];
    out[i*3+1] = pos[s*3+1];
    out[i*3+2] = pos[s*3+2];
  }
}
__global__ void k_inv_build(const int* __restrict__ fp, int* __restrict__ inv, int n2){
  int i = blockIdx.x*256 + threadIdx.x;
  if (i < n2) inv[fp[i]] = i;
}

// ---------------- concatenated CSR build ----------------
__global__ void k_countA(const int* __restrict__ d0, const int* __restrict__ d1,
                         const int* __restrict__ d2, int* cnt){
  int e = blockIdx.x*256 + threadIdx.x;
  if (e < E0)            atomicAdd(&cnt[d0[e]], 1);
  else if (e < E0+E1)    atomicAdd(&cnt[N0 + d1[e-E0]], 1);
  else if (e < ETOT)     atomicAdd(&cnt[N0+N1 + d2[e-E0-E1]], 1);
}
__global__ __launch_bounds__(256) void k_scan1(const int* __restrict__ cnt,
                                               int* __restrict__ excl,
                                               int* __restrict__ bsum){
  __shared__ int lds[256];
  int tid = threadIdx.x;
  int i = blockIdx.x*256 + tid;
  int v = cnt[i];
  lds[tid] = v;
  __syncthreads();
  for (int off = 1; off < 256; off <<= 1){
    int t = (tid >= off) ? lds[tid - off] : 0;
    __syncthreads();
    lds[tid] += t;
    __syncthreads();
  }
  excl[i] = lds[tid] - v;
  if (tid == 255) bsum[blockIdx.x] = lds[255];
}
__global__ __launch_bounds__(256) void k_scan2(int* bsum, int nb){
  __shared__ int lds[256];
  int tid = threadIdx.x;
  int v = (tid < nb) ? bsum[tid] : 0;
  lds[tid] = v;
  __syncthreads();
  for (int off = 1; off < 256; off <<= 1){
    int t = (tid >= off) ? lds[tid - off] : 0;
    __syncthreads();
    lds[tid] += t;
    __syncthreads();
  }
  if (tid < nb) bsum[tid] = lds[tid] - v;
}
__global__ __launch_bounds__(256) void k_scan3(const int* __restrict__ excl,
                                               const int* __restrict__ bsum,
                                               int* __restrict__ row,
                                               int* __restrict__ cur){
  int i = blockIdx.x*256 + threadIdx.x;
  int r = excl[i] + bsum[blockIdx.x];
  row[i] = r; cur[i] = r;
  if (i == 0) row[NTOT] = ETOT;
}
__global__ void k_scatter_geoA(const int* __restrict__ s0, const int* __restrict__ d0,
                               const int* __restrict__ s1, const int* __restrict__ d1,
                               const int* __restrict__ s2, const int* __restrict__ d2,
                               const float* __restrict__ pos0, const float* __restrict__ pos1,
                               const float* __restrict__ pos2, int* cur,
                               int* __restrict__ srcs, float4* __restrict__ meta){
  int e = blockIdx.x*256 + threadIdx.x;
  if (e >= ETOT) return;
  int s, d, noff; const float* pos;
  if (e < E0)        { s = s0[e];        d = d0[e];        pos = pos0; noff = 0; }
  else if (e < E0+E1){ s = s1[e-E0];     d = d1[e-E0];     pos = pos1; noff = N0; }
  else               { s = s2[e-E0-E1];  d = d2[e-E0-E1];  pos = pos2; noff = N0+N1; }
  float dx = pos[d*3+0]-pos[s*3+0];
  float dy = pos[d*3+1]-pos[s*3+1];
  float dz = pos[d*3+2]-pos[s*3+2];
  int p = atomicAdd(&cur[noff + d], 1);
  srcs[p] = s;
  meta[p] = make_float4(sqrtf(dx*dx+dy*dy+dz*dz+1e-12f), dx, dy, dz);
}

// ---------------- layer-9 radial bias precompute (for the head loop) ----
__global__ __launch_bounds__(256) void k_rbias(const float4* __restrict__ meta,
                                               const float* __restrict__ w1,
                                               const float* __restrict__ w2,
                                               float* __restrict__ rb, int nE){
  int e = blockIdx.x*256 + threadIdx.x;
  if (e >= nE) return;
  float r = meta[e].x;
  float a = 0.f;
  #pragma unroll
  for (int j = 0; j < 16; ++j) a += fmaxf(r*w1[j], 0.f)*w2[j];
  rb[e] = a;
}

// ---------------- transform: q, packed-kv (bf16), skip (Cout=32) ----------------
// mode 0: x plain | mode 1: POOL x=sum/(cnt+EPS) | mode 2: UPS x=base+up[inv]
__global__ __launch_bounds__(256) void k_transformF(
    const float* __restrict__ x, const float* __restrict__ cntv,
    const float* __restrict__ up, const int* __restrict__ inv,
    const float* __restrict__ Wq, const float* __restrict__ Wk,
    const float* __restrict__ Wv, const float* __restrict__ Ws,
    float* __restrict__ q, unsigned* __restrict__ kv, float* __restrict__ s,
    int n, int Cin, int mode){
  __shared__ float wI[4096];
  __shared__ float xr4[8][128];
  __shared__ float kvst[8][192];
  int tid = threadIdx.x;
  int nw = Cin * 32;
  for (int i = tid; i < nw; i += 256){
    wI[i*4+0] = Wq[i]; wI[i*4+1] = Wk[i]; wI[i*4+2] = Wv[i]; wI[i*4+3] = Ws[i];
  }
  int g = tid >> 5, lane = tid & 31;
  int node = blockIdx.x*8 + g;
  int xl = Cin * 3;
  if (node < n){
    if (mode == 1){
      float ic = 1.f / (cntv[node] + EPS);
      for (int c = lane; c < Cin; c += 32){
        int b = node*xl + c*3;
        xr4[g][c*4+0] = x[b+0]*ic; xr4[g][c*4+1] = x[b+1]*ic; xr4[g][c*4+2] = x[b+2]*ic;
      }
    } else if (mode == 2){
      int a = inv[node];
      for (int c = lane; c < Cin; c += 32){
        int b = node*xl + c*3;
        float v0_ = x[b], v1_ = x[b+1], v2_ = x[b+2];
        if (a >= 0){
          size_t ub = (size_t)a*xl + c*3;
          v0_ += up[ub]; v1_ += up[ub+1]; v2_ += up[ub+2];
        }
        xr4[g][c*4+0] = v0_; xr4[g][c*4+1] = v1_; xr4[g][c*4+2] = v2_;
      }
    } else {
      for (int c = lane; c < Cin; c += 32){
        int b = node*xl + c*3;
        xr4[g][c*4+0] = x[b]; xr4[g][c*4+1] = x[b+1]; xr4[g][c*4+2] = x[b+2];
      }
    }
  }
  __syncthreads();
  if (node < n){
    float aq0=0.f,aq1=0.f,aq2=0.f, ak0=0.f,ak1=0.f,ak2=0.f;
    float aw0=0.f,aw1=0.f,aw2=0.f, as0=0.f,as1=0.f,as2=0.f;
    for (int c = 0; c < Cin; ++c){
      float4 xv = *(const float4*)&xr4[g][c*4];
      float4 wv = *(const float4*)&wI[(c*32+lane)*4];
      aq0 += xv.x*wv.x; aq1 += xv.y*wv.x; aq2 += xv.z*wv.x;
      ak0 += xv.x*wv.y; ak1 += xv.y*wv.y; ak2 += xv.z*wv.y;
      aw0 += xv.x*wv.z; aw1 += xv.y*wv.z; aw2 += xv.z*wv.z;
      as0 += xv.x*wv.w; as1 += xv.y*wv.w; as2 += xv.z*wv.w;
    }
    int o = node*96 + lane*3;
    q[o]=aq0; q[o+1]=aq1; q[o+2]=aq2;
    s[o]=as0; s[o+1]=as1; s[o+2]=as2;
    kvst[g][lane*3+0]=ak0; kvst[g][lane*3+1]=ak1; kvst[g][lane*3+2]=ak2;
    kvst[g][96+lane*3+0]=aw0; kvst[g][96+lane*3+1]=aw1; kvst[g][96+lane*3+2]=aw2;
    float2 p0 = *(const float2*)&kvst[g][2*lane];
    float2 p1 = *(const float2*)&kvst[g][64+2*lane];
    float2 p2 = *(const float2*)&kvst[g][128+2*lane];
    *(uint2*)(kv + (size_t)node*96 + 2*lane) = make_uint2(bfpack(p0.x,p0.y), bfpack(p1.x,p1.y));
    kv[(size_t)node*96 + 64 + lane] = bfpack(p2.x, p2.y);
  }
}

// ---------------- attention core (R3/R8-proven 4-wide loop, DPP reduce, uint2 KV) ----------------
#define ATTN_CORE(QB,KVB,SB) \
  float rw1 = (lane < 16) ? wr1[lane] : 0.f; \
  float rw2 = (lane < 16) ? wr2[lane] : 0.f; \
  float ql0=0.f, ql1=0.f, ql2=0.f, ql3=0.f; \
  float z=0.f, av0=0.f, av1=0.f, av2=0.f, av3=0.f, R0=0.f, R1=0.f, R2=0.f; \
  int beg=0, end=0; \
  if (act){ \
    int nb = node*96; \
    float2 qa = *(const float2*)(QB + nb + 2*lane); \
    ql0 = qa.x*invsc; ql1 = qa.y*invsc; \
    if (lane < 16){ \
      float2 qc = *(const float2*)(QB + nb + 64 + 2*lane); \
      ql2 = qc.x*invsc; ql3 = qc.y*invsc; \
    } \
    beg = row[node]; end = row[node+1]; \
  } \
  for (int cb = beg; cb < end; cb += 32){ \
    int csz = end - cb; if (csz > 32) csz = 32; \
    int sn_l = 0; float4 mt = make_float4(0.f,0.f,0.f,0.f); \
    if (lane < csz){ \
      int idx = cb + lane; \
      sn_l = srcs[idx]; \
      mt = meta[idx]; \
    } \
    for (int j = 0; j < csz; j += 4){ \
      int gs = csz - j; if (gs > 4) gs = 4; \
      int sid[4]; float rrB[4]; \
      _Pragma("unroll") \
      for (int t = 0; t < 4; ++t){ \
        int sl = (j + t) & 31; \
        sid[t] = __shfl(sn_l, sl, 32); \
        rrB[t] = __shfl(mt.x, sl, 32); \
      } \
      unsigned d0[4], d1[4], d2[4]; \
      _Pragma("unroll") \
      for (int t = 0; t < 4; ++t){ \
        const unsigned* kp = KVB + (size_t)sid[t]*96; \
        bool ok = t < gs; \
        uint2 ab = ok ? *(const uint2*)(kp + 2*lane) : make_uint2(0u,0u); \
        d0[t] = ab.x; d1[t] = ab.y; \
        d2[t] = ok ? kp[64 + lane] : 0u; \
      } \
      _Pragma("unroll") \
      for (int t = 0; t < 4; ++t){ \
        float pt = bf_lo(d0[t])*ql0 + bf_hi(d0[t])*ql1; \
        if (lane < 16) pt += bf_lo(d1[t])*ql2 + bf_hi(d1[t])*ql3; \
        pt += fmaxf(rrB[t]*rw1, 0.f) * rw2; \
        pt = grp32_sum(pt); \
        float w = (t < gs) ? __expf(fminf(pt, 80.f)) : 0.f; \
        z += w; \
        av0 += w*bf_lo(d2[t]); av1 += w*bf_hi(d2[t]); \
        if (lane >= 16){ av2 += w*bf_lo(d1[t]); av3 += w*bf_hi(d1[t]); } \
        if (lane == j + t){ R0 += w*mt.y; R1 += w*mt.z; R2 += w*mt.w; } \
      } \
    } \
  } \
  R0 = grp32_sum(R0); \
  R1 = grp32_sum(R1); \
  R2 = grp32_sum(R2); \
  if (act){ \
    vsum[g][2*lane+32] = av0; \
    vsum[g][2*lane+33] = av1; \
    if (lane >= 16){ vsum[g][2*lane-32] = av2; vsum[g][2*lane-31] = av3; } \
  } \
  float y0=0.f, y1=0.f, y2=0.f; \
  if (act){ \
    float invz = 1.f / (z + EPS); \
    int base = node*96 + 3*lane; \
    y0 = (vsum[g][3*lane+0] + R0)*invz + SB[base]; \
    y1 = (vsum[g][3*lane+1] + R1)*invz + SB[base+1]; \
    y2 = (vsum[g][3*lane+2] + R2)*invz + SB[base+2]; \
    float nrm = sqrtf(y0*y0 + y1*y1 + y2*y2 + 1e-12f); \
    float f = fmaxf(scaleA[lane]*nrm + biasA[lane], 0.f) / nrm; \
    y0 *= f; y1 *= f; y2 *= f; \
  }

// ---------------- plain attention (odd layers): writes y, optional fused pool ----------------
__global__ __launch_bounds__(256) void k_attn32(
    const float* __restrict__ qb, const unsigned* __restrict__ kvb,
    const float* __restrict__ sb,
    const int* __restrict__ row, const int* __restrict__ srcs,
    const float4* __restrict__ meta,
    const float* __restrict__ wr1, const float* __restrict__ wr2,
    const float* __restrict__ scaleA, const float* __restrict__ biasA,
    float* __restrict__ outb,
    float* psum, float* pcnt_, const int* __restrict__ cl,
    int n, float invsc){
  __shared__ float vsum[8][96];
  int tid = threadIdx.x, g = tid >> 5, lane = tid & 31;
  int node = blockIdx.x*8 + g;
  bool act = node < n;
  ATTN_CORE(qb, kvb, sb)
  if (act){
    int base = node*96 + 3*lane;
    outb[base]   = y0;
    outb[base+1] = y1;
    outb[base+2] = y2;
    if (cl){                        // fused segment-sum pooling
      int c = cl[node];
      atomicAdd(&psum[c*96 + 3*lane],   y0);
      atomicAdd(&psum[c*96 + 3*lane+1], y1);
      atomicAdd(&psum[c*96 + 3*lane+2], y2);
      if (lane == 0) atomicAdd(&pcnt_[c], 1.f);
    }
  }
}

// ---------------- fused attention + next-layer transform (Cout=32) ----------------
__global__ __launch_bounds__(256) void k_attn32_t32(
    float* __restrict__ qb, const unsigned* __restrict__ kvin,
    float* __restrict__ sb,
    const int* __restrict__ row, const int* __restrict__ srcs,
    const float4* __restrict__ meta,
    const float* __restrict__ wr1, const float* __restrict__ wr2,
    const float* __restrict__ scaleA, const float* __restrict__ biasA,
    const float* __restrict__ Wq2, const float* __restrict__ Wk2,
    const float* __restrict__ Wv2, const float* __restrict__ Ws2,
    unsigned* __restrict__ kvout, int n, float invsc){
  __shared__ float vsum[8][96];
  __shared__ float wI[4096];
  __shared__ float kvst[8][192];
  int tid = threadIdx.x, g = tid >> 5, lane = tid & 31;
  for (int i = tid; i < 1024; i += 256){
    wI[i*4+0] = Wq2[i]; wI[i*4+1] = Wk2[i]; wI[i*4+2] = Wv2[i]; wI[i*4+3] = Ws2[i];
  }
  int node = blockIdx.x*8 + g;
  bool act = node < n;
  ATTN_CORE(qb, kvin, sb)
  __syncthreads();
  if (act){
    vsum[g][3*lane+0] = y0;
    vsum[g][3*lane+1] = y1;
    vsum[g][3*lane+2] = y2;
    float aq0=0.f,aq1=0.f,aq2=0.f, ak0=0.f,ak1=0.f,ak2=0.f;
    float aw0=0.f,aw1=0.f,aw2=0.f, as0=0.f,as1=0.f,as2=0.f;
    for (int c = 0; c < 32; ++c){
      float x0 = vsum[g][c*3+0], x1 = vsum[g][c*3+1], x2 = vsum[g][c*3+2];
      float4 wv = *(const float4*)&wI[(c*32+lane)*4];
      aq0 += x0*wv.x;  aq1 += x1*wv.x;  aq2 += x2*wv.x;
      ak0 += x0*wv.y;  ak1 += x1*wv.y;  ak2 += x2*wv.y;
      aw0 += x0*wv.z;  aw1 += x1*wv.z;  aw2 += x2*wv.z;
      as0 += x0*wv.w;  as1 += x1*wv.w;  as2 += x2*wv.w;
    }
    int ob = node*96 + 3*lane;
    qb[ob]=aq0; qb[ob+1]=aq1; qb[ob+2]=aq2;
    sb[ob]=as0; sb[ob+1]=as1; sb[ob+2]=as2;
    kvst[g][lane*3+0]=ak0; kvst[g][lane*3+1]=ak1; kvst[g][lane*3+2]=ak2;
    kvst[g][96+lane*3+0]=aw0; kvst[g][96+lane*3+1]=aw1; kvst[g][96+lane*3+2]=aw2;
    float2 p0 = *(const float2*)&kvst[g][2*lane];
    float2 p1 = *(const float2*)&kvst[g][64+2*lane];
    float2 p2 = *(const float2*)&kvst[g][128+2*lane];
    *(uint2*)(kvout + (size_t)node*96 + 2*lane) = make_uint2(bfpack(p0.x,p0.y), bfpack(p1.x,p1.y));
    kvout[(size_t)node*96 + 64 + lane] = bfpack(p2.x, p2.y);
  }
}

// ---------------- fused attention + Cout=1 transform (pair 8,9) ----------------
__global__ __launch_bounds__(256) void k_attn32_t1(
    const float* __restrict__ qb, const unsigned* __restrict__ kvin,
    const float* __restrict__ sb,
    const int* __restrict__ row, const int* __restrict__ srcs,
    const float4* __restrict__ meta,
    const float* __restrict__ wr1, const float* __restrict__ wr2,
    const float* __restrict__ scaleA, const float* __restrict__ biasA,
    const float* __restrict__ Wq2, const float* __restrict__ Wk2,
    const float* __restrict__ Wv2, const float* __restrict__ Ws2,
    float* __restrict__ q1, float* __restrict__ kv1,
    float* __restrict__ s1,
    int n, float invsc){
  __shared__ float vsum[8][96];
  int tid = threadIdx.x, g = tid >> 5, lane = tid & 31;
  int node = blockIdx.x*8 + g;
  bool act = node < n;
  ATTN_CORE(qb, kvin, sb)
  if (act){
    vsum[g][3*lane+0] = y0;
    vsum[g][3*lane+1] = y1;
    vsum[g][3*lane+2] = y2;
  }
  if (act && lane < 12){
    int m = lane / 3, v = lane - m*3;
    const float* W = (m==0) ? Wq2 : (m==1) ? Wk2 : (m==2) ? Wv2 : Ws2;
    float a = 0.f;
    for (int c = 0; c < 32; ++c) a += vsum[g][c*3+v] * W[c];
    if (m==0)      q1[node*3 + v] = a;
    else if (m==1) kv1[(size_t)node*8 + v] = a;       // k at [0..2]
    else if (m==2) kv1[(size_t)node*8 + 3 + v] = a;   // v at [3..5]
    else           s1[node*3 + v] = a;
  }
}

// ---------------- Cout=1 attention fused with MLP head (8 lanes/node) ----------------
__global__ __launch_bounds__(256) void k_attn1_head(
    const float* __restrict__ qb, const float* __restrict__ kv1,
    const float* __restrict__ sb, const float* __restrict__ rb9,
    const int* __restrict__ row, const int* __restrict__ srcs,
    const float4* __restrict__ meta,
    const float* __restrict__ scaleA, const float* __restrict__ biasA,
    const float* __restrict__ Wmlp,
    float* __restrict__ out, int n, float invsc){
  __shared__ float w[120];
  int tid = threadIdx.x;
  if (tid < 120) w[tid] = Wmlp[tid];
  __syncthreads();
  int i = blockIdx.x*32 + (tid >> 3);   // 32 nodes per block, 8 lanes each
  int lane8 = tid & 7;
  if (i >= n) return;
  float q0 = qb[i*3]*invsc, q1 = qb[i*3+1]*invsc, q2 = qb[i*3+2]*invsc;
  float z = 0.f, a0 = 0.f, a1 = 0.f, a2 = 0.f;
  int beg = row[i], end = row[i+1];
  for (int e = beg + lane8; e < end; e += 8){
    int s = srcs[e];
    float4 m = meta[e];
    float4 A = *(const float4*)(kv1 + (size_t)s*8);      // k0,k1,k2,v0
    float2 B = *(const float2*)(kv1 + (size_t)s*8 + 4);  // v1,v2
    float pt = q0*A.x + q1*A.y + q2*A.z + rb9[e];
    float wgt = __expf(fminf(pt, 80.f));
    z += wgt;
    a0 += wgt*(A.w + m.y); a1 += wgt*(B.x + m.z); a2 += wgt*(B.y + m.w);
  }
  // butterfly reduce across the 8 lanes of this node
  #pragma unroll
  for (int xm = 1; xm <= 4; xm <<= 1){
    z  += __shfl_xor(z,  xm, 8);
    a0 += __shfl_xor(a0, xm, 8);
    a1 += __shfl_xor(a1, xm, 8);
    a2 += __shfl_xor(a2, xm, 8);
  }
  float invz = 1.f / (z + EPS);
  float y0 = a0*invz + sb[i*3];
  float y1 = a1*invz + sb[i*3+1];
  float y2 = a2*invz + sb[i*3+2];
  float nrm = sqrtf(y0*y0 + y1*y1 + y2*y2 + 1e-12f);
  float f = fmaxf(scaleA[0]*nrm + biasA[0], 0.f) / nrm;
  y0 *= f; y1 *= f; y2 *= f;
  #pragma unroll
  for (int c = 0; c < 5; ++c){
    int o2 = lane8*5 + c;
    out[(size_t)i*40 + o2] = fmaxf(y0*w[o2] + y1*w[40+o2] + y2*w[80+o2], 0.f);
  }
}

extern "C" void kernel_launch(void* const* d_in, const int* in_sizes, int n_in,
                              void* d_out, int out_size, void* d_ws, size_t ws_size,
                              hipStream_t stream){
  const float* pos0      = (const float*)d_in[0];
  const float* v0        = (const float*)d_in[1];
  const float* Wq_first  = (const float*)d_in[2];
  const float* Wk_first  = (const float*)d_in[3];
  const float* Wv_first  = (const float*)d_in[4];
  const float* Ws_first  = (const float*)d_in[5];
  const float* Wq_mid    = (const float*)d_in[6];
  const float* Wk_mid    = (const float*)d_in[7];
  const float* Wv_mid    = (const float*)d_in[8];
  const float* Ws_mid    = (const float*)d_in[9];
  const float* Wq_last   = (const float*)d_in[10];
  const float* Wk_last   = (const float*)d_in[11];
  const float* Wv_last   = (const float*)d_in[12];
  const float* Ws_last   = (const float*)d_in[13];
  const float* wr1       = (const float*)d_in[14];
  const float* wr2       = (const float*)d_in[15];
  const float* scale_mid = (const float*)d_in[16];
  const float* bias_mid  = (const float*)d_in[17];
  const float* scale_last= (const float*)d_in[18];
  const float* bias_last = (const float*)d_in[19];
  const float* Wmlp      = (const float*)d_in[20];
  const int* src0 = (const int*)d_in[21];
  const int* dst0 = (const int*)d_in[22];
  const int* src1 = (const int*)d_in[23];
  const int* dst1 = (const int*)d_in[24];
  const int* src2 = (const int*)d_in[25];
  const int* dst2 = (const int*)d_in[26];
  const int* fp1  = (const int*)d_in[27];
  const int* fp2  = (const int*)d_in[28];
  const int* cl1  = (const int*)d_in[29];
  const int* cl2  = (const int*)d_in[30];

  float* ws = (float*)d_ws;
  size_t o = 0;
  float* xA   = ws + o; o += (size_t)N0*96;   // scratch fiber (attn5/attn7 outputs)
  float* x0s  = ws + o; o += (size_t)N0*96;   // level-0 skip
  float* x1s  = ws + o; o += (size_t)N1*96;   // level-1 skip
  float* xP1  = ws + o; o += (size_t)N1*96;   // pool-1 sums
  float* xP2  = ws + o; o += (size_t)N2*96;   // pool-2 sums
  float* qb   = ws + o; o += (size_t)N0*96;
  float* sb   = ws + o; o += (size_t)N0*96;
  unsigned* kvb  = (unsigned*)(ws + o); o += (size_t)N0*96;
  unsigned* kvb2 = (unsigned*)(ws + o); o += (size_t)N0*96;
  float4* metaA = (float4*)(ws + o); o += (size_t)ETOT*4;
  float* q1v  = ws + o; o += (size_t)N0*3;
  float* s1v  = ws + o; o += (size_t)N0*3;
  float* kv1  = ws + o; o += (size_t)N0*8;    // packed k(3),v(3),pad(2)
  float* rb9  = ws + o; o += (size_t)E0;      // layer-9 radial bias per level-0 edge
  float* pcnt1 = ws + o; o += N1;
  float* pcnt2 = ws + o; o += N2;
  float* pos1 = ws + o; o += (size_t)N1*3;
  float* pos2 = ws + o; o += (size_t)N2*3;
  int* ib = (int*)(ws + o);
  size_t io = 0;
  int* rowA  = ib + io; io += NTOT+1;
  int* cntA  = ib + io; io += NTOT;
  int* curA  = ib + io; io += NTOT;
  int* exclA = ib + io; io += NTOT;
  int* bsumA = ib + io; io += 256;
  int* srcsA = ib + io; io += ETOT;
  int* inv0  = ib + io; io += N0;
  int* inv1  = ib + io; io += N1;

  // ---- zero pool accumulators up-front (graph-safe, before any attn writes) ----
  hipMemsetAsync(xP1, 0, (size_t)N1*96*sizeof(float), stream);
  hipMemsetAsync(xP2, 0, (size_t)N2*96*sizeof(float), stream);
  hipMemsetAsync(pcnt1, 0, N1*sizeof(float), stream);
  hipMemsetAsync(pcnt2, 0, N2*sizeof(float), stream);
  hipMemsetAsync(inv0, 0xFF, N0*sizeof(int), stream);
  hipMemsetAsync(inv1, 0xFF, N1*sizeof(int), stream);
  hipMemsetAsync(cntA, 0, NTOT*sizeof(int), stream);

  k_gather_pos<<<cdiv(N1,256),256,0,stream>>>(pos0, fp1, pos1, N1);
  k_gather_pos<<<cdiv(N2,256),256,0,stream>>>(pos1, fp2, pos2, N2);
  k_inv_build<<<cdiv(N1,256),256,0,stream>>>(fp1, inv0, N1);
  k_inv_build<<<cdiv(N2,256),256,0,stream>>>(fp2, inv1, N2);

  k_countA<<<cdiv(ETOT,256),256,0,stream>>>(dst0, dst1, dst2, cntA);
  k_scan1<<<NBLK,256,0,stream>>>(cntA, exclA, bsumA);
  k_scan2<<<1,256,0,stream>>>(bsumA, NBLK);
  k_scan3<<<NBLK,256,0,stream>>>(exclA, bsumA, rowA, curA);
  k_scatter_geoA<<<cdiv(ETOT,256),256,0,stream>>>(src0, dst0, src1, dst1, src2, dst2,
                                                  pos0, pos1, pos2, curA, srcsA, metaA);
  k_rbias<<<cdiv(E0,256),256,0,stream>>>(metaA, wr1 + 9*16, wr2 + 9*16, rb9, E0);

  const float invsc = 1.f / sqrtf(96.f);
  const int C = 32;

  // pair driver: T_even(mode), attn_even+T_odd, attn_odd(+pool)
  auto pair32 = [&](const float* xin, const float* cntv, const float* up, const int* inv,
                    int mode, int n, int nodeBase, int Cin,
                    const float* WqE, const float* WkE, const float* WvE, const float* WsE,
                    const float* WqO, const float* WkO, const float* WvO, const float* WsO,
                    int lE, float* xout,
                    float* psum, float* pcnt_, const int* cl){
    k_transformF<<<cdiv(n,8),256,0,stream>>>(xin, cntv, up, inv, WqE, WkE, WvE, WsE,
                                             qb, kvb, sb, n, Cin, mode);
    k_attn32_t32<<<cdiv(n,8),256,0,stream>>>(qb, kvb, sb, rowA + nodeBase, srcsA, metaA,
                                             wr1 + lE*16, wr2 + lE*16,
                                             scale_mid + lE*C, bias_mid + lE*C,
                                             WqO, WkO, WvO, WsO, kvb2, n, invsc);
    k_attn32<<<cdiv(n,8),256,0,stream>>>(qb, kvb2, sb, rowA + nodeBase, srcsA, metaA,
                                         wr1 + (lE+1)*16, wr2 + (lE+1)*16,
                                         scale_mid + (lE+1)*C, bias_mid + (lE+1)*C,
                                         xout, psum, pcnt_, cl, n, invsc);
  };

  // pair (0,1) level 0 -> x0s, fused pool into xP1/pcnt1
  pair32(v0, nullptr, nullptr, nullptr, 0, N0, 0, 1,
         Wq_first, Wk_first, Wv_first, Ws_first,
         Wq_mid+0*1024, Wk_mid+0*1024, Wv_mid+0*1024, Ws_mid+0*1024,
         0, x0s, xP1, pcnt1, cl1);
  // pair (2,3) level 1 (POOL input) -> x1s, fused pool into xP2/pcnt2
  pair32(xP1, pcnt1, nullptr, nullptr, 1, N1, N0, C,
         Wq_mid+1*1024, Wk_mid+1*1024, Wv_mid+1*1024, Ws_mid+1*1024,
         Wq_mid+2*1024, Wk_mid+2*1024, Wv_mid+2*1024, Ws_mid+2*1024,
         2, x1s, xP2, pcnt2, cl2);
  // pair (4,5) level 2 (POOL input) -> xA (N2 rows)
  pair32(xP2, pcnt2, nullptr, nullptr, 1, N2, N0+N1, C,
         Wq_mid+3*1024, Wk_mid+3*1024, Wv_mid+3*1024, Ws_mid+3*1024,
         Wq_mid+4*1024, Wk_mid+4*1024, Wv_mid+4*1024, Ws_mid+4*1024,
         4, xA, nullptr, nullptr, nullptr);
  // pair (6,7) level 1 (UPS input: x1s + xA[inv1]) -> xA (N1 rows)
  pair32(x1s, nullptr, xA, inv1, 2, N1, N0, C,
         Wq_mid+5*1024, Wk_mid+5*1024, Wv_mid+5*1024, Ws_mid+5*1024,
         Wq_mid+6*1024, Wk_mid+6*1024, Wv_mid+6*1024, Ws_mid+6*1024,
         6, xA, nullptr, nullptr, nullptr);
  // pair (8,9): T8 (UPS input: x0s + xA[inv0]), attn8+T9(Cout=1), attn9+head
  k_transformF<<<cdiv(N0,8),256,0,stream>>>(x0s, nullptr, xA, inv0,
                                            Wq_mid+7*1024, Wk_mid+7*1024,
                                            Wv_mid+7*1024, Ws_mid+7*1024,
                                            qb, kvb, sb, N0, C, 2);
  k_attn32_t1<<<cdiv(N0,8),256,0,stream>>>(qb, kvb, sb, rowA, srcsA, metaA,
                                           wr1 + 8*16, wr2 + 8*16,
                                           scale_mid + 8*C, bias_mid + 8*C,
                                           Wq_last, Wk_last, Wv_last, Ws_last,
                                           q1v, kv1, s1v, N0, invsc);
  {
    float invsc1 = 1.f / sqrtf(3.f);
    k_attn1_head<<<cdiv(N0,32),256,0,stream>>>(q1v, kv1, s1v, rb9, rowA, srcsA, metaA,
                                               scale_last, bias_last,
                                               Wmlp, (float*)d_out, N0, invsc1);
  }
}

// Round 15
// 403.003 us; speedup vs baseline: 1.1136x; 1.0743x over previous
//
#include <hip/hip_runtime.h>
#include <math.h>

#define N0 32768
#define N1 8192
#define N2 2048
#define E0 262144
#define E1 65536
#define E2 16384
#define NTOT (N0+N1+N2)     // 43008
#define ETOT (E0+E1+E2)     // 344064
#define NBLK (NTOT/256)     // 168
#define EPS 1e-9f

static inline int cdiv(int a, int b){ return (a + b - 1) / b; }

__device__ inline unsigned bfpack(float a, float b){
  unsigned ua = __float_as_uint(a), ub = __float_as_uint(b);
  ua = (ua + 0x7fffu + ((ua >> 16) & 1u)) >> 16;
  ub = (ub + 0x7fffu + ((ub >> 16) & 1u)) & 0xffff0000u;
  return ua | ub;
}
__device__ inline float bf_lo(unsigned d){ return __uint_as_float(d << 16); }
__device__ inline float bf_hi(unsigned d){ return __uint_as_float(d & 0xffff0000u); }

// 32-lane-group full sum, DPP rotate-reduce (VALU) + one ds_swizzle xor16.
__device__ inline float grp32_sum(float x){
  x += __int_as_float(__builtin_amdgcn_update_dpp(0, __float_as_int(x), 0x121, 0xf, 0xf, true)); // ror:1
  x += __int_as_float(__builtin_amdgcn_update_dpp(0, __float_as_int(x), 0x122, 0xf, 0xf, true)); // ror:2
  x += __int_as_float(__builtin_amdgcn_update_dpp(0, __float_as_int(x), 0x124, 0xf, 0xf, true)); // ror:4
  x += __int_as_float(__builtin_amdgcn_update_dpp(0, __float_as_int(x), 0x128, 0xf, 0xf, true)); // ror:8
  x += __int_as_float(__builtin_amdgcn_ds_swizzle(__float_as_int(x), 0x401F));                   // xor:16
  return x;
}

// ---------------- fused setup: edge counts + inv maps ----------------
__global__ void k_setup(const int* __restrict__ d0, const int* __restrict__ d1,
                        const int* __restrict__ d2,
                        const int* __restrict__ fp1, const int* __restrict__ fp2,
                        int* cnt, int* __restrict__ inv0, int* __restrict__ inv1){
  int e = blockIdx.x*256 + threadIdx.x;
  if (e < E0)            atomicAdd(&cnt[d0[e]], 1);
  else if (e < E0+E1)    atomicAdd(&cnt[N0 + d1[e-E0]], 1);
  else if (e < ETOT)     atomicAdd(&cnt[N0+N1 + d2[e-E0-E1]], 1);
  if (e < N1) inv0[fp1[e]] = e;
  if (e < N2) inv1[fp2[e]] = e;
}
__global__ __launch_bounds__(256) void k_scan1(const int* __restrict__ cnt,
                                               int* __restrict__ excl,
                                               int* __restrict__ bsum){
  __shared__ int lds[256];
  int tid = threadIdx.x;
  int i = blockIdx.x*256 + tid;
  int v = cnt[i];
  lds[tid] = v;
  __syncthreads();
  for (int off = 1; off < 256; off <<= 1){
    int t = (tid >= off) ? lds[tid - off] : 0;
    __syncthreads();
    lds[tid] += t;
    __syncthreads();
  }
  excl[i] = lds[tid] - v;
  if (tid == 255) bsum[blockIdx.x] = lds[255];
}
// fused scan2+scan3: each block computes its own bsum-prefix (168 entries)
__global__ __launch_bounds__(256) void k_scan23(const int* __restrict__ excl,
                                                const int* __restrict__ bsum,
                                                int* __restrict__ row,
                                                int* __restrict__ cur){
  __shared__ int lds[256];
  int tid = threadIdx.x;
  int v = (tid < (int)blockIdx.x && tid < NBLK) ? bsum[tid] : 0;
  lds[tid] = v;
  __syncthreads();
  for (int off = 1; off < 256; off <<= 1){
    int t = (tid >= off) ? lds[tid - off] : 0;
    __syncthreads();
    lds[tid] += t;
    __syncthreads();
  }
  int offset = lds[255];              // sum of bsum[0..blockIdx.x)
  int i = blockIdx.x*256 + tid;
  int r = excl[i] + offset;
  row[i] = r; cur[i] = r;
  if (i == 0) row[NTOT] = ETOT;
}
// scatter with on-the-fly positions (pos1[i]=pos0[fp1[i]], pos2[i]=pos0[fp1[fp2[i]]])
// and fused layer-9 radial bias for level-0 slots (p < E0).
__global__ void k_scatter_geoA(const int* __restrict__ s0, const int* __restrict__ d0,
                               const int* __restrict__ s1, const int* __restrict__ d1,
                               const int* __restrict__ s2, const int* __restrict__ d2,
                               const float* __restrict__ pos0,
                               const int* __restrict__ fp1, const int* __restrict__ fp2,
                               const float* __restrict__ w1, const float* __restrict__ w2,
                               int* cur, int* __restrict__ srcs, float4* __restrict__ meta,
                               float* __restrict__ rb9){
  int e = blockIdx.x*256 + threadIdx.x;
  if (e >= ETOT) return;
  int s, d, noff, sp, dp;
  if (e < E0){
    s = s0[e]; d = d0[e]; noff = 0;
    sp = s; dp = d;
  } else if (e < E0+E1){
    s = s1[e-E0]; d = d1[e-E0]; noff = N0;
    sp = fp1[s]; dp = fp1[d];
  } else {
    s = s2[e-E0-E1]; d = d2[e-E0-E1]; noff = N0+N1;
    sp = fp1[fp2[s]]; dp = fp1[fp2[d]];
  }
  float dx = pos0[dp*3+0]-pos0[sp*3+0];
  float dy = pos0[dp*3+1]-pos0[sp*3+1];
  float dz = pos0[dp*3+2]-pos0[sp*3+2];
  float r = sqrtf(dx*dx+dy*dy+dz*dz+1e-12f);
  int p = atomicAdd(&cur[noff + d], 1);
  srcs[p] = s;
  meta[p] = make_float4(r, dx, dy, dz);
  if (p < E0){                       // level-0 slot: layer-9 radial bias
    float a = 0.f;
    #pragma unroll
    for (int j = 0; j < 16; ++j) a += fmaxf(r*w1[j], 0.f)*w2[j];
    rb9[p] = a;
  }
}

// ---------------- transform: q, packed-kv (bf16), skip (Cout=32) ----------------
// mode 0: x plain | mode 1: POOL x=sum/(cnt+EPS) | mode 2: UPS x=base+up[inv]
__global__ __launch_bounds__(256) void k_transformF(
    const float* __restrict__ x, const float* __restrict__ cntv,
    const float* __restrict__ up, const int* __restrict__ inv,
    const float* __restrict__ Wq, const float* __restrict__ Wk,
    const float* __restrict__ Wv, const float* __restrict__ Ws,
    float* __restrict__ q, unsigned* __restrict__ kv, float* __restrict__ s,
    int n, int Cin, int mode){
  __shared__ float wI[4096];
  __shared__ float xr4[8][128];
  __shared__ float kvst[8][192];
  int tid = threadIdx.x;
  int nw = Cin * 32;
  for (int i = tid; i < nw; i += 256){
    wI[i*4+0] = Wq[i]; wI[i*4+1] = Wk[i]; wI[i*4+2] = Wv[i]; wI[i*4+3] = Ws[i];
  }
  int g = tid >> 5, lane = tid & 31;
  int node = blockIdx.x*8 + g;
  int xl = Cin * 3;
  if (node < n){
    if (mode == 1){
      float ic = 1.f / (cntv[node] + EPS);
      for (int c = lane; c < Cin; c += 32){
        int b = node*xl + c*3;
        xr4[g][c*4+0] = x[b+0]*ic; xr4[g][c*4+1] = x[b+1]*ic; xr4[g][c*4+2] = x[b+2]*ic;
      }
    } else if (mode == 2){
      int a = inv[node];
      for (int c = lane; c < Cin; c += 32){
        int b = node*xl + c*3;
        float v0_ = x[b], v1_ = x[b+1], v2_ = x[b+2];
        if (a >= 0){
          size_t ub = (size_t)a*xl + c*3;
          v0_ += up[ub]; v1_ += up[ub+1]; v2_ += up[ub+2];
        }
        xr4[g][c*4+0] = v0_; xr4[g][c*4+1] = v1_; xr4[g][c*4+2] = v2_;
      }
    } else {
      for (int c = lane; c < Cin; c += 32){
        int b = node*xl + c*3;
        xr4[g][c*4+0] = x[b]; xr4[g][c*4+1] = x[b+1]; xr4[g][c*4+2] = x[b+2];
      }
    }
  }
  __syncthreads();
  if (node < n){
    float aq0=0.f,aq1=0.f,aq2=0.f, ak0=0.f,ak1=0.f,ak2=0.f;
    float aw0=0.f,aw1=0.f,aw2=0.f, as0=0.f,as1=0.f,as2=0.f;
    for (int c = 0; c < Cin; ++c){
      float4 xv = *(const float4*)&xr4[g][c*4];
      float4 wv = *(const float4*)&wI[(c*32+lane)*4];
      aq0 += xv.x*wv.x; aq1 += xv.y*wv.x; aq2 += xv.z*wv.x;
      ak0 += xv.x*wv.y; ak1 += xv.y*wv.y; ak2 += xv.z*wv.y;
      aw0 += xv.x*wv.z; aw1 += xv.y*wv.z; aw2 += xv.z*wv.z;
      as0 += xv.x*wv.w; as1 += xv.y*wv.w; as2 += xv.z*wv.w;
    }
    int o = node*96 + lane*3;
    q[o]=aq0; q[o+1]=aq1; q[o+2]=aq2;
    s[o]=as0; s[o+1]=as1; s[o+2]=as2;
    kvst[g][lane*3+0]=ak0; kvst[g][lane*3+1]=ak1; kvst[g][lane*3+2]=ak2;
    kvst[g][96+lane*3+0]=aw0; kvst[g][96+lane*3+1]=aw1; kvst[g][96+lane*3+2]=aw2;
    float2 p0 = *(const float2*)&kvst[g][2*lane];
    float2 p1 = *(const float2*)&kvst[g][64+2*lane];
    float2 p2 = *(const float2*)&kvst[g][128+2*lane];
    *(uint2*)(kv + (size_t)node*96 + 2*lane) = make_uint2(bfpack(p0.x,p0.y), bfpack(p1.x,p1.y));
    kv[(size_t)node*96 + 64 + lane] = bfpack(p2.x, p2.y);
  }
}

// ---------------- attention core (R3/R8-proven 4-wide loop, DPP reduce, uint2 KV) ----------------
#define ATTN_CORE(QB,KVB,SB) \
  float rw1 = (lane < 16) ? wr1[lane] : 0.f; \
  float rw2 = (lane < 16) ? wr2[lane] : 0.f; \
  float ql0=0.f, ql1=0.f, ql2=0.f, ql3=0.f; \
  float z=0.f, av0=0.f, av1=0.f, av2=0.f, av3=0.f, R0=0.f, R1=0.f, R2=0.f; \
  int beg=0, end=0; \
  if (act){ \
    int nb = node*96; \
    float2 qa = *(const float2*)(QB + nb + 2*lane); \
    ql0 = qa.x*invsc; ql1 = qa.y*invsc; \
    if (lane < 16){ \
      float2 qc = *(const float2*)(QB + nb + 64 + 2*lane); \
      ql2 = qc.x*invsc; ql3 = qc.y*invsc; \
    } \
    beg = row[node]; end = row[node+1]; \
  } \
  for (int cb = beg; cb < end; cb += 32){ \
    int csz = end - cb; if (csz > 32) csz = 32; \
    int sn_l = 0; float4 mt = make_float4(0.f,0.f,0.f,0.f); \
    if (lane < csz){ \
      int idx = cb + lane; \
      sn_l = srcs[idx]; \
      mt = meta[idx]; \
    } \
    for (int j = 0; j < csz; j += 4){ \
      int gs = csz - j; if (gs > 4) gs = 4; \
      int sid[4]; float rrB[4]; \
      _Pragma("unroll") \
      for (int t = 0; t < 4; ++t){ \
        int sl = (j + t) & 31; \
        sid[t] = __shfl(sn_l, sl, 32); \
        rrB[t] = __shfl(mt.x, sl, 32); \
      } \
      unsigned d0[4], d1[4], d2[4]; \
      _Pragma("unroll") \
      for (int t = 0; t < 4; ++t){ \
        const unsigned* kp = KVB + (size_t)sid[t]*96; \
        bool ok = t < gs; \
        uint2 ab = ok ? *(const uint2*)(kp + 2*lane) : make_uint2(0u,0u); \
        d0[t] = ab.x; d1[t] = ab.y; \
        d2[t] = ok ? kp[64 + lane] : 0u; \
      } \
      _Pragma("unroll") \
      for (int t = 0; t < 4; ++t){ \
        float pt = bf_lo(d0[t])*ql0 + bf_hi(d0[t])*ql1; \
        if (lane < 16) pt += bf_lo(d1[t])*ql2 + bf_hi(d1[t])*ql3; \
        pt += fmaxf(rrB[t]*rw1, 0.f) * rw2; \
        pt = grp32_sum(pt); \
        float w = (t < gs) ? __expf(fminf(pt, 80.f)) : 0.f; \
        z += w; \
        av0 += w*bf_lo(d2[t]); av1 += w*bf_hi(d2[t]); \
        if (lane >= 16){ av2 += w*bf_lo(d1[t]); av3 += w*bf_hi(d1[t]); } \
        if (lane == j + t){ R0 += w*mt.y; R1 += w*mt.z; R2 += w*mt.w; } \
      } \
    } \
  } \
  R0 = grp32_sum(R0); \
  R1 = grp32_sum(R1); \
  R2 = grp32_sum(R2); \
  if (act){ \
    vsum[g][2*lane+32] = av0; \
    vsum[g][2*lane+33] = av1; \
    if (lane >= 16){ vsum[g][2*lane-32] = av2; vsum[g][2*lane-31] = av3; } \
  } \
  float y0=0.f, y1=0.f, y2=0.f; \
  if (act){ \
    float invz = 1.f / (z + EPS); \
    int base = node*96 + 3*lane; \
    y0 = (vsum[g][3*lane+0] + R0)*invz + SB[base]; \
    y1 = (vsum[g][3*lane+1] + R1)*invz + SB[base+1]; \
    y2 = (vsum[g][3*lane+2] + R2)*invz + SB[base+2]; \
    float nrm = sqrtf(y0*y0 + y1*y1 + y2*y2 + 1e-12f); \
    float f = fmaxf(scaleA[lane]*nrm + biasA[lane], 0.f) / nrm; \
    y0 *= f; y1 *= f; y2 *= f; \
  }

// ---------------- plain attention (odd layers): writes y, optional fused pool ----------------
__global__ __launch_bounds__(256) void k_attn32(
    const float* __restrict__ qb, const unsigned* __restrict__ kvb,
    const float* __restrict__ sb,
    const int* __restrict__ row, const int* __restrict__ srcs,
    const float4* __restrict__ meta,
    const float* __restrict__ wr1, const float* __restrict__ wr2,
    const float* __restrict__ scaleA, const float* __restrict__ biasA,
    float* __restrict__ outb,
    float* psum, float* pcnt_, const int* __restrict__ cl,
    int n, float invsc){
  __shared__ float vsum[8][96];
  int tid = threadIdx.x, g = tid >> 5, lane = tid & 31;
  int node = blockIdx.x*8 + g;
  bool act = node < n;
  ATTN_CORE(qb, kvb, sb)
  if (act){
    int base = node*96 + 3*lane;
    outb[base]   = y0;
    outb[base+1] = y1;
    outb[base+2] = y2;
    if (cl){                        // fused segment-sum pooling
      int c = cl[node];
      atomicAdd(&psum[c*96 + 3*lane],   y0);
      atomicAdd(&psum[c*96 + 3*lane+1], y1);
      atomicAdd(&psum[c*96 + 3*lane+2], y2);
      if (lane == 0) atomicAdd(&pcnt_[c], 1.f);
    }
  }
}

// ---------------- fused attention + next-layer transform (Cout=32) ----------------
__global__ __launch_bounds__(256) void k_attn32_t32(
    float* __restrict__ qb, const unsigned* __restrict__ kvin,
    float* __restrict__ sb,
    const int* __restrict__ row, const int* __restrict__ srcs,
    const float4* __restrict__ meta,
    const float* __restrict__ wr1, const float* __restrict__ wr2,
    const float* __restrict__ scaleA, const float* __restrict__ biasA,
    const float* __restrict__ Wq2, const float* __restrict__ Wk2,
    const float* __restrict__ Wv2, const float* __restrict__ Ws2,
    unsigned* __restrict__ kvout, int n, float invsc){
  __shared__ float vsum[8][96];
  __shared__ float wI[4096];
  __shared__ float kvst[8][192];
  int tid = threadIdx.x, g = tid >> 5, lane = tid & 31;
  for (int i = tid; i < 1024; i += 256){
    wI[i*4+0] = Wq2[i]; wI[i*4+1] = Wk2[i]; wI[i*4+2] = Wv2[i]; wI[i*4+3] = Ws2[i];
  }
  int node = blockIdx.x*8 + g;
  bool act = node < n;
  ATTN_CORE(qb, kvin, sb)
  __syncthreads();
  if (act){
    vsum[g][3*lane+0] = y0;
    vsum[g][3*lane+1] = y1;
    vsum[g][3*lane+2] = y2;
    float aq0=0.f,aq1=0.f,aq2=0.f, ak0=0.f,ak1=0.f,ak2=0.f;
    float aw0=0.f,aw1=0.f,aw2=0.f, as0=0.f,as1=0.f,as2=0.f;
    for (int c = 0; c < 32; ++c){
      float x0 = vsum[g][c*3+0], x1 = vsum[g][c*3+1], x2 = vsum[g][c*3+2];
      float4 wv = *(const float4*)&wI[(c*32+lane)*4];
      aq0 += x0*wv.x;  aq1 += x1*wv.x;  aq2 += x2*wv.x;
      ak0 += x0*wv.y;  ak1 += x1*wv.y;  ak2 += x2*wv.y;
      aw0 += x0*wv.z;  aw1 += x1*wv.z;  aw2 += x2*wv.z;
      as0 += x0*wv.w;  as1 += x1*wv.w;  as2 += x2*wv.w;
    }
    int ob = node*96 + 3*lane;
    qb[ob]=aq0; qb[ob+1]=aq1; qb[ob+2]=aq2;
    sb[ob]=as0; sb[ob+1]=as1; sb[ob+2]=as2;
    kvst[g][lane*3+0]=ak0; kvst[g][lane*3+1]=ak1; kvst[g][lane*3+2]=ak2;
    kvst[g][96+lane*3+0]=aw0; kvst[g][96+lane*3+1]=aw1; kvst[g][96+lane*3+2]=aw2;
    float2 p0 = *(const float2*)&kvst[g][2*lane];
    float2 p1 = *(const float2*)&kvst[g][64+2*lane];
    float2 p2 = *(const float2*)&kvst[g][128+2*lane];
    *(uint2*)(kvout + (size_t)node*96 + 2*lane) = make_uint2(bfpack(p0.x,p0.y), bfpack(p1.x,p1.y));
    kvout[(size_t)node*96 + 64 + lane] = bfpack(p2.x, p2.y);
  }
}

// ---------------- fused attention + Cout=1 transform (pair 8,9) ----------------
__global__ __launch_bounds__(256) void k_attn32_t1(
    const float* __restrict__ qb, const unsigned* __restrict__ kvin,
    const float* __restrict__ sb,
    const int* __restrict__ row, const int* __restrict__ srcs,
    const float4* __restrict__ meta,
    const float* __restrict__ wr1, const float* __restrict__ wr2,
    const float* __restrict__ scaleA, const float* __restrict__ biasA,
    const float* __restrict__ Wq2, const float* __restrict__ Wk2,
    const float* __restrict__ Wv2, const float* __restrict__ Ws2,
    float* __restrict__ q1, float* __restrict__ kv1,
    float* __restrict__ s1,
    int n, float invsc){
  __shared__ float vsum[8][96];
  int tid = threadIdx.x, g = tid >> 5, lane = tid & 31;
  int node = blockIdx.x*8 + g;
  bool act = node < n;
  ATTN_CORE(qb, kvin, sb)
  if (act){
    vsum[g][3*lane+0] = y0;
    vsum[g][3*lane+1] = y1;
    vsum[g][3*lane+2] = y2;
  }
  if (act && lane < 12){
    int m = lane / 3, v = lane - m*3;
    const float* W = (m==0) ? Wq2 : (m==1) ? Wk2 : (m==2) ? Wv2 : Ws2;
    float a = 0.f;
    for (int c = 0; c < 32; ++c) a += vsum[g][c*3+v] * W[c];
    if (m==0)      q1[node*3 + v] = a;
    else if (m==1) kv1[(size_t)node*8 + v] = a;       // k at [0..2]
    else if (m==2) kv1[(size_t)node*8 + 3 + v] = a;   // v at [3..5]
    else           s1[node*3 + v] = a;
  }
}

// ---------------- Cout=1 attention fused with MLP head (8 lanes/node) ----------------
__global__ __launch_bounds__(256) void k_attn1_head(
    const float* __restrict__ qb, const float* __restrict__ kv1,
    const float* __restrict__ sb, const float* __restrict__ rb9,
    const int* __restrict__ row, const int* __restrict__ srcs,
    const float4* __restrict__ meta,
    const float* __restrict__ scaleA, const float* __restrict__ biasA,
    const float* __restrict__ Wmlp,
    float* __restrict__ out, int n, float invsc){
  __shared__ float w[120];
  int tid = threadIdx.x;
  if (tid < 120) w[tid] = Wmlp[tid];
  __syncthreads();
  int i = blockIdx.x*32 + (tid >> 3);   // 32 nodes per block, 8 lanes each
  int lane8 = tid & 7;
  if (i >= n) return;
  float q0 = qb[i*3]*invsc, q1 = qb[i*3+1]*invsc, q2 = qb[i*3+2]*invsc;
  float z = 0.f, a0 = 0.f, a1 = 0.f, a2 = 0.f;
  int beg = row[i], end = row[i+1];
  for (int e = beg + lane8; e < end; e += 8){
    int s = srcs[e];
    float4 m = meta[e];
    float4 A = *(const float4*)(kv1 + (size_t)s*8);      // k0,k1,k2,v0
    float2 B = *(const float2*)(kv1 + (size_t)s*8 + 4);  // v1,v2
    float pt = q0*A.x + q1*A.y + q2*A.z + rb9[e];
    float wgt = __expf(fminf(pt, 80.f));
    z += wgt;
    a0 += wgt*(A.w + m.y); a1 += wgt*(B.x + m.z); a2 += wgt*(B.y + m.w);
  }
  // butterfly reduce across the 8 lanes of this node
  #pragma unroll
  for (int xm = 1; xm <= 4; xm <<= 1){
    z  += __shfl_xor(z,  xm, 8);
    a0 += __shfl_xor(a0, xm, 8);
    a1 += __shfl_xor(a1, xm, 8);
    a2 += __shfl_xor(a2, xm, 8);
  }
  float invz = 1.f / (z + EPS);
  float y0 = a0*invz + sb[i*3];
  float y1 = a1*invz + sb[i*3+1];
  float y2 = a2*invz + sb[i*3+2];
  float nrm = sqrtf(y0*y0 + y1*y1 + y2*y2 + 1e-12f);
  float f = fmaxf(scaleA[0]*nrm + biasA[0], 0.f) / nrm;
  y0 *= f; y1 *= f; y2 *= f;
  #pragma unroll
  for (int c = 0; c < 5; ++c){
    int o2 = lane8*5 + c;
    out[(size_t)i*40 + o2] = fmaxf(y0*w[o2] + y1*w[40+o2] + y2*w[80+o2], 0.f);
  }
}

extern "C" void kernel_launch(void* const* d_in, const int* in_sizes, int n_in,
                              void* d_out, int out_size, void* d_ws, size_t ws_size,
                              hipStream_t stream){
  const float* pos0      = (const float*)d_in[0];
  const float* v0        = (const float*)d_in[1];
  const float* Wq_first  = (const float*)d_in[2];
  const float* Wk_first  = (const float*)d_in[3];
  const float* Wv_first  = (const float*)d_in[4];
  const float* Ws_first  = (const float*)d_in[5];
  const float* Wq_mid    = (const float*)d_in[6];
  const float* Wk_mid    = (const float*)d_in[7];
  const float* Wv_mid    = (const float*)d_in[8];
  const float* Ws_mid    = (const float*)d_in[9];
  const float* Wq_last   = (const float*)d_in[10];
  const float* Wk_last   = (const float*)d_in[11];
  const float* Wv_last   = (const float*)d_in[12];
  const float* Ws_last   = (const float*)d_in[13];
  const float* wr1       = (const float*)d_in[14];
  const float* wr2       = (const float*)d_in[15];
  const float* scale_mid = (const float*)d_in[16];
  const float* bias_mid  = (const float*)d_in[17];
  const float* scale_last= (const float*)d_in[18];
  const float* bias_last = (const float*)d_in[19];
  const float* Wmlp      = (const float*)d_in[20];
  const int* src0 = (const int*)d_in[21];
  const int* dst0 = (const int*)d_in[22];
  const int* src1 = (const int*)d_in[23];
  const int* dst1 = (const int*)d_in[24];
  const int* src2 = (const int*)d_in[25];
  const int* dst2 = (const int*)d_in[26];
  const int* fp1  = (const int*)d_in[27];
  const int* fp2  = (const int*)d_in[28];
  const int* cl1  = (const int*)d_in[29];
  const int* cl2  = (const int*)d_in[30];

  float* ws = (float*)d_ws;
  size_t o = 0;
  float* xA   = ws + o; o += (size_t)N0*96;   // scratch fiber (attn5/attn7 outputs)
  float* x0s  = ws + o; o += (size_t)N0*96;   // level-0 skip
  float* x1s  = ws + o; o += (size_t)N1*96;   // level-1 skip
  float* qb   = ws + o; o += (size_t)N0*96;
  float* sb   = ws + o; o += (size_t)N0*96;
  unsigned* kvb  = (unsigned*)(ws + o); o += (size_t)N0*96;
  unsigned* kvb2 = (unsigned*)(ws + o); o += (size_t)N0*96;
  float4* metaA = (float4*)(ws + o); o += (size_t)ETOT*4;
  float* q1v  = ws + o; o += (size_t)N0*3;
  float* s1v  = ws + o; o += (size_t)N0*3;
  float* kv1  = ws + o; o += (size_t)N0*8;    // packed k(3),v(3),pad(2)
  float* rb9  = ws + o; o += (size_t)E0;      // layer-9 radial bias per level-0 slot
  // ---- contiguous ZERO zone (single memset 0) ----
  float* zz   = ws + o;
  float* xP1  = ws + o; o += (size_t)N1*96;   // pool-1 sums
  float* xP2  = ws + o; o += (size_t)N2*96;   // pool-2 sums
  float* pcnt1 = ws + o; o += N1;
  float* pcnt2 = ws + o; o += N2;
  int* cntA = (int*)(ws + o); o += NTOT;
  size_t zz_bytes = ((size_t)N1*96 + N2*96 + N1 + N2 + NTOT) * sizeof(float);
  // ---- remaining int buffers ----
  int* ib = (int*)(ws + o);
  size_t io = 0;
  int* rowA  = ib + io; io += NTOT+1;
  int* curA  = ib + io; io += NTOT;
  int* exclA = ib + io; io += NTOT;
  int* bsumA = ib + io; io += 256;
  int* srcsA = ib + io; io += ETOT;
  // ---- contiguous 0xFF zone (single memset) ----
  int* inv0  = ib + io; io += N0;
  int* inv1  = ib + io; io += N1;
  size_t ff_bytes = ((size_t)N0 + N1) * sizeof(int);

  // ---- 2 memsets (was 7): zero zone + inv zone ----
  hipMemsetAsync(zz, 0, zz_bytes, stream);
  hipMemsetAsync(inv0, 0xFF, ff_bytes, stream);

  // ---- fused setup (counts + inv maps), scans, scatter(+rbias, on-the-fly pos) ----
  k_setup<<<cdiv(ETOT,256),256,0,stream>>>(dst0, dst1, dst2, fp1, fp2, cntA, inv0, inv1);
  k_scan1<<<NBLK,256,0,stream>>>(cntA, exclA, bsumA);
  k_scan23<<<NBLK,256,0,stream>>>(exclA, bsumA, rowA, curA);
  k_scatter_geoA<<<cdiv(ETOT,256),256,0,stream>>>(src0, dst0, src1, dst1, src2, dst2,
                                                  pos0, fp1, fp2,
                                                  wr1 + 9*16, wr2 + 9*16,
                                                  curA, srcsA, metaA, rb9);

  const float invsc = 1.f / sqrtf(96.f);
  const int C = 32;

  // pair driver: T_even(mode), attn_even+T_odd, attn_odd(+pool)
  auto pair32 = [&](const float* xin, const float* cntv, const float* up, const int* inv,
                    int mode, int n, int nodeBase, int Cin,
                    const float* WqE, const float* WkE, const float* WvE, const float* WsE,
                    const float* WqO, const float* WkO, const float* WvO, const float* WsO,
                    int lE, float* xout,
                    float* psum, float* pcnt_, const int* cl){
    k_transformF<<<cdiv(n,8),256,0,stream>>>(xin, cntv, up, inv, WqE, WkE, WvE, WsE,
                                             qb, kvb, sb, n, Cin, mode);
    k_attn32_t32<<<cdiv(n,8),256,0,stream>>>(qb, kvb, sb, rowA + nodeBase, srcsA, metaA,
                                             wr1 + lE*16, wr2 + lE*16,
                                             scale_mid + lE*C, bias_mid + lE*C,
                                             WqO, WkO, WvO, WsO, kvb2, n, invsc);
    k_attn32<<<cdiv(n,8),256,0,stream>>>(qb, kvb2, sb, rowA + nodeBase, srcsA, metaA,
                                         wr1 + (lE+1)*16, wr2 + (lE+1)*16,
                                         scale_mid + (lE+1)*C, bias_mid + (lE+1)*C,
                                         xout, psum, pcnt_, cl, n, invsc);
  };

  // pair (0,1) level 0 -> x0s, fused pool into xP1/pcnt1
  pair32(v0, nullptr, nullptr, nullptr, 0, N0, 0, 1,
         Wq_first, Wk_first, Wv_first, Ws_first,
         Wq_mid+0*1024, Wk_mid+0*1024, Wv_mid+0*1024, Ws_mid+0*1024,
         0, x0s, xP1, pcnt1, cl1);
  // pair (2,3) level 1 (POOL input) -> x1s, fused pool into xP2/pcnt2
  pair32(xP1, pcnt1, nullptr, nullptr, 1, N1, N0, C,
         Wq_mid+1*1024, Wk_mid+1*1024, Wv_mid+1*1024, Ws_mid+1*1024,
         Wq_mid+2*1024, Wk_mid+2*1024, Wv_mid+2*1024, Ws_mid+2*1024,
         2, x1s, xP2, pcnt2, cl2);
  // pair (4,5) level 2 (POOL input) -> xA (N2 rows)
  pair32(xP2, pcnt2, nullptr, nullptr, 1, N2, N0+N1, C,
         Wq_mid+3*1024, Wk_mid+3*1024, Wv_mid+3*1024, Ws_mid+3*1024,
         Wq_mid+4*1024, Wk_mid+4*1024, Wv_mid+4*1024, Ws_mid+4*1024,
         4, xA, nullptr, nullptr, nullptr);
  // pair (6,7) level 1 (UPS input: x1s + xA[inv1]) -> xA (N1 rows)
  pair32(x1s, nullptr, xA, inv1, 2, N1, N0, C,
         Wq_mid+5*1024, Wk_mid+5*1024, Wv_mid+5*1024, Ws_mid+5*1024,
         Wq_mid+6*1024, Wk_mid+6*1024, Wv_mid+6*1024, Ws_mid+6*1024,
         6, xA, nullptr, nullptr, nullptr);
  // pair (8,9): T8 (UPS input: x0s + xA[inv0]), attn8+T9(Cout=1), attn9+head
  k_transformF<<<cdiv(N0,8),256,0,stream>>>(x0s, nullptr, xA, inv0,
                                            Wq_mid+7*1024, Wk_mid+7*1024,
                                            Wv_mid+7*1024, Ws_mid+7*1024,
                                            qb, kvb, sb, N0, C, 2);
  k_attn32_t1<<<cdiv(N0,8),256,0,stream>>>(qb, kvb, sb, rowA, srcsA, metaA,
                                           wr1 + 8*16, wr2 + 8*16,
                                           scale_mid + 8*C, bias_mid + 8*C,
                                           Wq_last, Wk_last, Wv_last, Ws_last,
                                           q1v, kv1, s1v, N0, invsc);
  {
    float invsc1 = 1.f / sqrtf(3.f);
    k_attn1_head<<<cdiv(N0,32),256,0,stream>>>(q1v, kv1, s1v, rb9, rowA, srcsA, metaA,
                                               scale_last, bias_last,
                                               Wmlp, (float*)d_out, N0, invsc1);
  }
}

// Round 16
// 386.142 us; speedup vs baseline: 1.1622x; 1.0437x over previous
//
#include <hip/hip_runtime.h>
#include <math.h>

#define N0 32768
#define N1 8192
#define N2 2048
#define E0 262144
#define E1 65536
#define E2 16384
#define NTOT (N0+N1+N2)     // 43008
#define ETOT (E0+E1+E2)     // 344064
#define DTOT (NTOT+N1+N2)   // 53248 = 208*256 (edge-dst nodes ++ cluster1 ++ cluster2)
#define NBLK2 (DTOT/256)    // 208
#define SLOTS (ETOT+N0+N1)  // 385024 (edge slots ++ cluster1 members ++ cluster2 members)
#define EPS 1e-9f

static inline int cdiv(int a, int b){ return (a + b - 1) / b; }

__device__ inline unsigned bfpack(float a, float b){
  unsigned ua = __float_as_uint(a), ub = __float_as_uint(b);
  ua = (ua + 0x7fffu + ((ua >> 16) & 1u)) >> 16;
  ub = (ub + 0x7fffu + ((ub >> 16) & 1u)) & 0xffff0000u;
  return ua | ub;
}
__device__ inline float bf_lo(unsigned d){ return __uint_as_float(d << 16); }
__device__ inline float bf_hi(unsigned d){ return __uint_as_float(d & 0xffff0000u); }

// 32-lane-group full sum, DPP rotate-reduce (VALU) + one ds_swizzle xor16.
__device__ inline float grp32_sum(float x){
  x += __int_as_float(__builtin_amdgcn_update_dpp(0, __float_as_int(x), 0x121, 0xf, 0xf, true)); // ror:1
  x += __int_as_float(__builtin_amdgcn_update_dpp(0, __float_as_int(x), 0x122, 0xf, 0xf, true)); // ror:2
  x += __int_as_float(__builtin_amdgcn_update_dpp(0, __float_as_int(x), 0x124, 0xf, 0xf, true)); // ror:4
  x += __int_as_float(__builtin_amdgcn_update_dpp(0, __float_as_int(x), 0x128, 0xf, 0xf, true)); // ror:8
  x += __int_as_float(__builtin_amdgcn_ds_swizzle(__float_as_int(x), 0x401F));                   // xor:16
  return x;
}

// ---------------- fused setup: edge counts + cluster counts + inv maps ----------------
__global__ void k_setup(const int* __restrict__ d0, const int* __restrict__ d1,
                        const int* __restrict__ d2,
                        const int* __restrict__ fp1, const int* __restrict__ fp2,
                        const int* __restrict__ cl1, const int* __restrict__ cl2,
                        int* cnt, int* __restrict__ inv0, int* __restrict__ inv1){
  int e = blockIdx.x*256 + threadIdx.x;
  if (e < E0)            atomicAdd(&cnt[d0[e]], 1);
  else if (e < E0+E1)    atomicAdd(&cnt[N0 + d1[e-E0]], 1);
  else if (e < ETOT)     atomicAdd(&cnt[N0+N1 + d2[e-E0-E1]], 1);
  if (e < N0) atomicAdd(&cnt[NTOT + cl1[e]], 1);          // cluster1 member counts
  if (e < N1){
    atomicAdd(&cnt[NTOT + N1 + cl2[e]], 1);               // cluster2 member counts
    inv0[fp1[e]] = e;
  }
  if (e < N2) inv1[fp2[e]] = e;
}
__global__ __launch_bounds__(256) void k_scan1(const int* __restrict__ cnt,
                                               int* __restrict__ excl,
                                               int* __restrict__ bsum){
  __shared__ int lds[256];
  int tid = threadIdx.x;
  int i = blockIdx.x*256 + tid;
  int v = cnt[i];
  lds[tid] = v;
  __syncthreads();
  for (int off = 1; off < 256; off <<= 1){
    int t = (tid >= off) ? lds[tid - off] : 0;
    __syncthreads();
    lds[tid] += t;
    __syncthreads();
  }
  excl[i] = lds[tid] - v;
  if (tid == 255) bsum[blockIdx.x] = lds[255];
}
// fused scan2+scan3: each block computes its own bsum-prefix (208 entries)
__global__ __launch_bounds__(256) void k_scan23(const int* __restrict__ excl,
                                                const int* __restrict__ bsum,
                                                int* __restrict__ row,
                                                int* __restrict__ cur){
  __shared__ int lds[256];
  int tid = threadIdx.x;
  int v = (tid < (int)blockIdx.x && tid < NBLK2) ? bsum[tid] : 0;
  lds[tid] = v;
  __syncthreads();
  for (int off = 1; off < 256; off <<= 1){
    int t = (tid >= off) ? lds[tid - off] : 0;
    __syncthreads();
    lds[tid] += t;
    __syncthreads();
  }
  int offset = lds[255];              // sum of bsum[0..blockIdx.x)
  int i = blockIdx.x*256 + tid;
  int r = excl[i] + offset;
  row[i] = r; cur[i] = r;
  if (i == 0) row[DTOT] = SLOTS;
}
// scatter: edge geometry (+rb9 on level-0 slots) AND cluster membership slots.
__global__ void k_scatter_geoA(const int* __restrict__ s0, const int* __restrict__ d0,
                               const int* __restrict__ s1, const int* __restrict__ d1,
                               const int* __restrict__ s2, const int* __restrict__ d2,
                               const float* __restrict__ pos0,
                               const int* __restrict__ fp1, const int* __restrict__ fp2,
                               const int* __restrict__ cl1, const int* __restrict__ cl2,
                               const float* __restrict__ w1, const float* __restrict__ w2,
                               int* cur, int* __restrict__ slots, float4* __restrict__ meta,
                               float* __restrict__ rb9){
  int e = blockIdx.x*256 + threadIdx.x;
  if (e >= ETOT) return;
  // cluster membership scatter (threads e<N0 / e<N1 double as member writers)
  if (e < N0){
    int p = atomicAdd(&cur[NTOT + cl1[e]], 1);
    slots[p] = e;
  }
  if (e < N1){
    int p = atomicAdd(&cur[NTOT + N1 + cl2[e]], 1);
    slots[p] = e;
  }
  int s, d, noff, sp, dp;
  if (e < E0){
    s = s0[e]; d = d0[e]; noff = 0;
    sp = s; dp = d;
  } else if (e < E0+E1){
    s = s1[e-E0]; d = d1[e-E0]; noff = N0;
    sp = fp1[s]; dp = fp1[d];
  } else {
    s = s2[e-E0-E1]; d = d2[e-E0-E1]; noff = N0+N1;
    sp = fp1[fp2[s]]; dp = fp1[fp2[d]];
  }
  float dx = pos0[dp*3+0]-pos0[sp*3+0];
  float dy = pos0[dp*3+1]-pos0[sp*3+1];
  float dz = pos0[dp*3+2]-pos0[sp*3+2];
  float r = sqrtf(dx*dx+dy*dy+dz*dz+1e-12f);
  int p = atomicAdd(&cur[noff + d], 1);
  slots[p] = s;
  meta[p] = make_float4(r, dx, dy, dz);
  if (p < E0){                       // level-0 slot: layer-9 radial bias
    float a = 0.f;
    #pragma unroll
    for (int j = 0; j < 16; ++j) a += fmaxf(r*w1[j], 0.f)*w2[j];
    rb9[p] = a;
  }
}

// ---------------- transform: q, packed-kv (bf16), skip (Cout=32) ----------------
// mode 0: x plain | mode 1: POOL x=mean over cluster members (CSR) | mode 2: UPS x=base+up[inv]
__global__ __launch_bounds__(256) void k_transformF(
    const float* __restrict__ x, const int* __restrict__ rowC, const int* __restrict__ slots,
    const float* __restrict__ up, const int* __restrict__ inv,
    const float* __restrict__ Wq, const float* __restrict__ Wk,
    const float* __restrict__ Wv, const float* __restrict__ Ws,
    float* __restrict__ q, unsigned* __restrict__ kv, float* __restrict__ s,
    int n, int Cin, int mode){
  __shared__ float wI[4096];
  __shared__ float xr4[8][128];
  __shared__ float kvst[8][192];
  int tid = threadIdx.x;
  int nw = Cin * 32;
  for (int i = tid; i < nw; i += 256){
    wI[i*4+0] = Wq[i]; wI[i*4+1] = Wk[i]; wI[i*4+2] = Wv[i]; wI[i*4+3] = Ws[i];
  }
  int g = tid >> 5, lane = tid & 31;
  int node = blockIdx.x*8 + g;
  int xl = Cin * 3;
  if (node < n){
    if (mode == 1){
      int mb = rowC[node], me = rowC[node+1];
      float ic = 1.f / ((float)(me - mb) + EPS);
      for (int c = lane; c < Cin; c += 32){
        float s0 = 0.f, s1 = 0.f, s2 = 0.f;
        for (int m = mb; m < me; ++m){
          int id = slots[m];
          int b = id*xl + c*3;
          s0 += x[b]; s1 += x[b+1]; s2 += x[b+2];
        }
        xr4[g][c*4+0] = s0*ic; xr4[g][c*4+1] = s1*ic; xr4[g][c*4+2] = s2*ic;
      }
    } else if (mode == 2){
      int a = inv[node];
      for (int c = lane; c < Cin; c += 32){
        int b = node*xl + c*3;
        float v0_ = x[b], v1_ = x[b+1], v2_ = x[b+2];
        if (a >= 0){
          size_t ub = (size_t)a*xl + c*3;
          v0_ += up[ub]; v1_ += up[ub+1]; v2_ += up[ub+2];
        }
        xr4[g][c*4+0] = v0_; xr4[g][c*4+1] = v1_; xr4[g][c*4+2] = v2_;
      }
    } else {
      for (int c = lane; c < Cin; c += 32){
        int b = node*xl + c*3;
        xr4[g][c*4+0] = x[b]; xr4[g][c*4+1] = x[b+1]; xr4[g][c*4+2] = x[b+2];
      }
    }
  }
  __syncthreads();
  if (node < n){
    float aq0=0.f,aq1=0.f,aq2=0.f, ak0=0.f,ak1=0.f,ak2=0.f;
    float aw0=0.f,aw1=0.f,aw2=0.f, as0=0.f,as1=0.f,as2=0.f;
    for (int c = 0; c < Cin; ++c){
      float4 xv = *(const float4*)&xr4[g][c*4];
      float4 wv = *(const float4*)&wI[(c*32+lane)*4];
      aq0 += xv.x*wv.x; aq1 += xv.y*wv.x; aq2 += xv.z*wv.x;
      ak0 += xv.x*wv.y; ak1 += xv.y*wv.y; ak2 += xv.z*wv.y;
      aw0 += xv.x*wv.z; aw1 += xv.y*wv.z; aw2 += xv.z*wv.z;
      as0 += xv.x*wv.w; as1 += xv.y*wv.w; as2 += xv.z*wv.w;
    }
    int o = node*96 + lane*3;
    q[o]=aq0; q[o+1]=aq1; q[o+2]=aq2;
    s[o]=as0; s[o+1]=as1; s[o+2]=as2;
    kvst[g][lane*3+0]=ak0; kvst[g][lane*3+1]=ak1; kvst[g][lane*3+2]=ak2;
    kvst[g][96+lane*3+0]=aw0; kvst[g][96+lane*3+1]=aw1; kvst[g][96+lane*3+2]=aw2;
    float2 p0 = *(const float2*)&kvst[g][2*lane];
    float2 p1 = *(const float2*)&kvst[g][64+2*lane];
    float2 p2 = *(const float2*)&kvst[g][128+2*lane];
    *(uint2*)(kv + (size_t)node*96 + 2*lane) = make_uint2(bfpack(p0.x,p0.y), bfpack(p1.x,p1.y));
    kv[(size_t)node*96 + 64 + lane] = bfpack(p2.x, p2.y);
  }
}

// ---------------- attention core (R3/R8-proven 4-wide loop, DPP reduce, uint2 KV) ----------------
#define ATTN_CORE(QB,KVB,SB) \
  float rw1 = (lane < 16) ? wr1[lane] : 0.f; \
  float rw2 = (lane < 16) ? wr2[lane] : 0.f; \
  float ql0=0.f, ql1=0.f, ql2=0.f, ql3=0.f; \
  float z=0.f, av0=0.f, av1=0.f, av2=0.f, av3=0.f, R0=0.f, R1=0.f, R2=0.f; \
  int beg=0, end=0; \
  if (act){ \
    int nb = node*96; \
    float2 qa = *(const float2*)(QB + nb + 2*lane); \
    ql0 = qa.x*invsc; ql1 = qa.y*invsc; \
    if (lane < 16){ \
      float2 qc = *(const float2*)(QB + nb + 64 + 2*lane); \
      ql2 = qc.x*invsc; ql3 = qc.y*invsc; \
    } \
    beg = row[node]; end = row[node+1]; \
  } \
  for (int cb = beg; cb < end; cb += 32){ \
    int csz = end - cb; if (csz > 32) csz = 32; \
    int sn_l = 0; float4 mt = make_float4(0.f,0.f,0.f,0.f); \
    if (lane < csz){ \
      int idx = cb + lane; \
      sn_l = srcs[idx]; \
      mt = meta[idx]; \
    } \
    for (int j = 0; j < csz; j += 4){ \
      int gs = csz - j; if (gs > 4) gs = 4; \
      int sid[4]; float rrB[4]; \
      _Pragma("unroll") \
      for (int t = 0; t < 4; ++t){ \
        int sl = (j + t) & 31; \
        sid[t] = __shfl(sn_l, sl, 32); \
        rrB[t] = __shfl(mt.x, sl, 32); \
      } \
      unsigned d0[4], d1[4], d2[4]; \
      _Pragma("unroll") \
      for (int t = 0; t < 4; ++t){ \
        const unsigned* kp = KVB + (size_t)sid[t]*96; \
        bool ok = t < gs; \
        uint2 ab = ok ? *(const uint2*)(kp + 2*lane) : make_uint2(0u,0u); \
        d0[t] = ab.x; d1[t] = ab.y; \
        d2[t] = ok ? kp[64 + lane] : 0u; \
      } \
      _Pragma("unroll") \
      for (int t = 0; t < 4; ++t){ \
        float pt = bf_lo(d0[t])*ql0 + bf_hi(d0[t])*ql1; \
        if (lane < 16) pt += bf_lo(d1[t])*ql2 + bf_hi(d1[t])*ql3; \
        pt += fmaxf(rrB[t]*rw1, 0.f) * rw2; \
        pt = grp32_sum(pt); \
        float w = (t < gs) ? __expf(fminf(pt, 80.f)) : 0.f; \
        z += w; \
        av0 += w*bf_lo(d2[t]); av1 += w*bf_hi(d2[t]); \
        if (lane >= 16){ av2 += w*bf_lo(d1[t]); av3 += w*bf_hi(d1[t]); } \
        if (lane == j + t){ R0 += w*mt.y; R1 += w*mt.z; R2 += w*mt.w; } \
      } \
    } \
  } \
  R0 = grp32_sum(R0); \
  R1 = grp32_sum(R1); \
  R2 = grp32_sum(R2); \
  if (act){ \
    vsum[g][2*lane+32] = av0; \
    vsum[g][2*lane+33] = av1; \
    if (lane >= 16){ vsum[g][2*lane-32] = av2; vsum[g][2*lane-31] = av3; } \
  } \
  float y0=0.f, y1=0.f, y2=0.f; \
  if (act){ \
    float invz = 1.f / (z + EPS); \
    int base = node*96 + 3*lane; \
    y0 = (vsum[g][3*lane+0] + R0)*invz + SB[base]; \
    y1 = (vsum[g][3*lane+1] + R1)*invz + SB[base+1]; \
    y2 = (vsum[g][3*lane+2] + R2)*invz + SB[base+2]; \
    float nrm = sqrtf(y0*y0 + y1*y1 + y2*y2 + 1e-12f); \
    float f = fmaxf(scaleA[lane]*nrm + biasA[lane], 0.f) / nrm; \
    y0 *= f; y1 *= f; y2 *= f; \
  }

// ---------------- plain attention (odd layers): writes y ----------------
__global__ __launch_bounds__(256) void k_attn32(
    const float* __restrict__ qb, const unsigned* __restrict__ kvb,
    const float* __restrict__ sb,
    const int* __restrict__ row, const int* __restrict__ srcs,
    const float4* __restrict__ meta,
    const float* __restrict__ wr1, const float* __restrict__ wr2,
    const float* __restrict__ scaleA, const float* __restrict__ biasA,
    float* __restrict__ outb,
    int n, float invsc){
  __shared__ float vsum[8][96];
  int tid = threadIdx.x, g = tid >> 5, lane = tid & 31;
  int node = blockIdx.x*8 + g;
  bool act = node < n;
  ATTN_CORE(qb, kvb, sb)
  if (act){
    int base = node*96 + 3*lane;
    outb[base]   = y0;
    outb[base+1] = y1;
    outb[base+2] = y2;
  }
}

// ---------------- fused attention + next-layer transform (Cout=32) ----------------
__global__ __launch_bounds__(256) void k_attn32_t32(
    float* __restrict__ qb, const unsigned* __restrict__ kvin,
    float* __restrict__ sb,
    const int* __restrict__ row, const int* __restrict__ srcs,
    const float4* __restrict__ meta,
    const float* __restrict__ wr1, const float* __restrict__ wr2,
    const float* __restrict__ scaleA, const float* __restrict__ biasA,
    const float* __restrict__ Wq2, const float* __restrict__ Wk2,
    const float* __restrict__ Wv2, const float* __restrict__ Ws2,
    unsigned* __restrict__ kvout, int n, float invsc){
  __shared__ float vsum[8][96];
  __shared__ float wI[4096];
  __shared__ float kvst[8][192];
  int tid = threadIdx.x, g = tid >> 5, lane = tid & 31;
  for (int i = tid; i < 1024; i += 256){
    wI[i*4+0] = Wq2[i]; wI[i*4+1] = Wk2[i]; wI[i*4+2] = Wv2[i]; wI[i*4+3] = Ws2[i];
  }
  int node = blockIdx.x*8 + g;
  bool act = node < n;
  ATTN_CORE(qb, kvin, sb)
  __syncthreads();
  if (act){
    vsum[g][3*lane+0] = y0;
    vsum[g][3*lane+1] = y1;
    vsum[g][3*lane+2] = y2;
    float aq0=0.f,aq1=0.f,aq2=0.f, ak0=0.f,ak1=0.f,ak2=0.f;
    float aw0=0.f,aw1=0.f,aw2=0.f, as0=0.f,as1=0.f,as2=0.f;
    for (int c = 0; c < 32; ++c){
      float x0 = vsum[g][c*3+0], x1 = vsum[g][c*3+1], x2 = vsum[g][c*3+2];
      float4 wv = *(const float4*)&wI[(c*32+lane)*4];
      aq0 += x0*wv.x;  aq1 += x1*wv.x;  aq2 += x2*wv.x;
      ak0 += x0*wv.y;  ak1 += x1*wv.y;  ak2 += x2*wv.y;
      aw0 += x0*wv.z;  aw1 += x1*wv.z;  aw2 += x2*wv.z;
      as0 += x0*wv.w;  as1 += x1*wv.w;  as2 += x2*wv.w;
    }
    int ob = node*96 + 3*lane;
    qb[ob]=aq0; qb[ob+1]=aq1; qb[ob+2]=aq2;
    sb[ob]=as0; sb[ob+1]=as1; sb[ob+2]=as2;
    kvst[g][lane*3+0]=ak0; kvst[g][lane*3+1]=ak1; kvst[g][lane*3+2]=ak2;
    kvst[g][96+lane*3+0]=aw0; kvst[g][96+lane*3+1]=aw1; kvst[g][96+lane*3+2]=aw2;
    float2 p0 = *(const float2*)&kvst[g][2*lane];
    float2 p1 = *(const float2*)&kvst[g][64+2*lane];
    float2 p2 = *(const float2*)&kvst[g][128+2*lane];
    *(uint2*)(kvout + (size_t)node*96 + 2*lane) = make_uint2(bfpack(p0.x,p0.y), bfpack(p1.x,p1.y));
    kvout[(size_t)node*96 + 64 + lane] = bfpack(p2.x, p2.y);
  }
}

// ---------------- fused attention + Cout=1 transform (pair 8,9) ----------------
__global__ __launch_bounds__(256) void k_attn32_t1(
    const float* __restrict__ qb, const unsigned* __restrict__ kvin,
    const float* __restrict__ sb,
    const int* __restrict__ row, const int* __restrict__ srcs,
    const float4* __restrict__ meta,
    const float* __restrict__ wr1, const float* __restrict__ wr2,
    const float* __restrict__ scaleA, const float* __restrict__ biasA,
    const float* __restrict__ Wq2, const float* __restrict__ Wk2,
    const float* __restrict__ Wv2, const float* __restrict__ Ws2,
    float* __restrict__ q1, float* __restrict__ kv1,
    float* __restrict__ s1,
    int n, float invsc){
  __shared__ float vsum[8][96];
  int tid = threadIdx.x, g = tid >> 5, lane = tid & 31;
  int node = blockIdx.x*8 + g;
  bool act = node < n;
  ATTN_CORE(qb, kvin, sb)
  if (act){
    vsum[g][3*lane+0] = y0;
    vsum[g][3*lane+1] = y1;
    vsum[g][3*lane+2] = y2;
  }
  if (act && lane < 12){
    int m = lane / 3, v = lane - m*3;
    const float* W = (m==0) ? Wq2 : (m==1) ? Wk2 : (m==2) ? Wv2 : Ws2;
    float a = 0.f;
    for (int c = 0; c < 32; ++c) a += vsum[g][c*3+v] * W[c];
    if (m==0)      q1[node*3 + v] = a;
    else if (m==1) kv1[(size_t)node*8 + v] = a;       // k at [0..2]
    else if (m==2) kv1[(size_t)node*8 + 3 + v] = a;   // v at [3..5]
    else           s1[node*3 + v] = a;
  }
}

// ---------------- Cout=1 attention fused with MLP head (8 lanes/node) ----------------
__global__ __launch_bounds__(256) void k_attn1_head(
    const float* __restrict__ qb, const float* __restrict__ kv1,
    const float* __restrict__ sb, const float* __restrict__ rb9,
    const int* __restrict__ row, const int* __restrict__ srcs,
    const float4* __restrict__ meta,
    const float* __restrict__ scaleA, const float* __restrict__ biasA,
    const float* __restrict__ Wmlp,
    float* __restrict__ out, int n, float invsc){
  __shared__ float w[120];
  int tid = threadIdx.x;
  if (tid < 120) w[tid] = Wmlp[tid];
  __syncthreads();
  int i = blockIdx.x*32 + (tid >> 3);   // 32 nodes per block, 8 lanes each
  int lane8 = tid & 7;
  if (i >= n) return;
  float q0 = qb[i*3]*invsc, q1 = qb[i*3+1]*invsc, q2 = qb[i*3+2]*invsc;
  float z = 0.f, a0 = 0.f, a1 = 0.f, a2 = 0.f;
  int beg = row[i], end = row[i+1];
  for (int e = beg + lane8; e < end; e += 8){
    int s = srcs[e];
    float4 m = meta[e];
    float4 A = *(const float4*)(kv1 + (size_t)s*8);      // k0,k1,k2,v0
    float2 B = *(const float2*)(kv1 + (size_t)s*8 + 4);  // v1,v2
    float pt = q0*A.x + q1*A.y + q2*A.z + rb9[e];
    float wgt = __expf(fminf(pt, 80.f));
    z += wgt;
    a0 += wgt*(A.w + m.y); a1 += wgt*(B.x + m.z); a2 += wgt*(B.y + m.w);
  }
  // butterfly reduce across the 8 lanes of this node
  #pragma unroll
  for (int xm = 1; xm <= 4; xm <<= 1){
    z  += __shfl_xor(z,  xm, 8);
    a0 += __shfl_xor(a0, xm, 8);
    a1 += __shfl_xor(a1, xm, 8);
    a2 += __shfl_xor(a2, xm, 8);
  }
  float invz = 1.f / (z + EPS);
  float y0 = a0*invz + sb[i*3];
  float y1 = a1*invz + sb[i*3+1];
  float y2 = a2*invz + sb[i*3+2];
  float nrm = sqrtf(y0*y0 + y1*y1 + y2*y2 + 1e-12f);
  float f = fmaxf(scaleA[0]*nrm + biasA[0], 0.f) / nrm;
  y0 *= f; y1 *= f; y2 *= f;
  #pragma unroll
  for (int c = 0; c < 5; ++c){
    int o2 = lane8*5 + c;
    out[(size_t)i*40 + o2] = fmaxf(y0*w[o2] + y1*w[40+o2] + y2*w[80+o2], 0.f);
  }
}

extern "C" void kernel_launch(void* const* d_in, const int* in_sizes, int n_in,
                              void* d_out, int out_size, void* d_ws, size_t ws_size,
                              hipStream_t stream){
  const float* pos0      = (const float*)d_in[0];
  const float* v0        = (const float*)d_in[1];
  const float* Wq_first  = (const float*)d_in[2];
  const float* Wk_first  = (const float*)d_in[3];
  const float* Wv_first  = (const float*)d_in[4];
  const float* Ws_first  = (const float*)d_in[5];
  const float* Wq_mid    = (const float*)d_in[6];
  const float* Wk_mid    = (const float*)d_in[7];
  const float* Wv_mid    = (const float*)d_in[8];
  const float* Ws_mid    = (const float*)d_in[9];
  const float* Wq_last   = (const float*)d_in[10];
  const float* Wk_last   = (const float*)d_in[11];
  const float* Wv_last   = (const float*)d_in[12];
  const float* Ws_last   = (const float*)d_in[13];
  const float* wr1       = (const float*)d_in[14];
  const float* wr2       = (const float*)d_in[15];
  const float* scale_mid = (const float*)d_in[16];
  const float* bias_mid  = (const float*)d_in[17];
  const float* scale_last= (const float*)d_in[18];
  const float* bias_last = (const float*)d_in[19];
  const float* Wmlp      = (const float*)d_in[20];
  const int* src0 = (const int*)d_in[21];
  const int* dst0 = (const int*)d_in[22];
  const int* src1 = (const int*)d_in[23];
  const int* dst1 = (const int*)d_in[24];
  const int* src2 = (const int*)d_in[25];
  const int* dst2 = (const int*)d_in[26];
  const int* fp1  = (const int*)d_in[27];
  const int* fp2  = (const int*)d_in[28];
  const int* cl1  = (const int*)d_in[29];
  const int* cl2  = (const int*)d_in[30];

  float* ws = (float*)d_ws;
  size_t o = 0;
  float* xA   = ws + o; o += (size_t)N0*96;   // scratch fiber (attn5/attn7 outputs)
  float* x0s  = ws + o; o += (size_t)N0*96;   // level-0 skip
  float* x1s  = ws + o; o += (size_t)N1*96;   // level-1 skip
  float* qb   = ws + o; o += (size_t)N0*96;
  float* sb   = ws + o; o += (size_t)N0*96;
  unsigned* kvb  = (unsigned*)(ws + o); o += (size_t)N0*96;
  unsigned* kvb2 = (unsigned*)(ws + o); o += (size_t)N0*96;
  float4* metaA = (float4*)(ws + o); o += (size_t)ETOT*4;
  float* q1v  = ws + o; o += (size_t)N0*3;
  float* s1v  = ws + o; o += (size_t)N0*3;
  float* kv1  = ws + o; o += (size_t)N0*8;    // packed k(3),v(3),pad(2)
  float* rb9  = ws + o; o += (size_t)E0;      // layer-9 radial bias per level-0 slot
  // ---- contiguous ZERO zone (single memset 0): concat counts ----
  int* cntA = (int*)(ws + o); o += DTOT;
  // ---- remaining int buffers ----
  int* ib = (int*)(ws + o);
  size_t io = 0;
  int* rowA  = ib + io; io += DTOT+1;
  int* curA  = ib + io; io += DTOT;
  int* exclA = ib + io; io += DTOT;
  int* bsumA = ib + io; io += 256;
  int* slotsA = ib + io; io += SLOTS;          // edges ++ cluster1 members ++ cluster2 members
  // ---- contiguous 0xFF zone (single memset) ----
  int* inv0  = ib + io; io += N0;
  int* inv1  = ib + io; io += N1;
  size_t ff_bytes = ((size_t)N0 + N1) * sizeof(int);

  // ---- 2 memsets: counts zero + inv 0xFF ----
  hipMemsetAsync(cntA, 0, (size_t)DTOT*sizeof(int), stream);
  hipMemsetAsync(inv0, 0xFF, ff_bytes, stream);

  // ---- fused setup (edge+cluster counts, inv maps), scans, scatter(+rbias+members) ----
  k_setup<<<cdiv(ETOT,256),256,0,stream>>>(dst0, dst1, dst2, fp1, fp2, cl1, cl2,
                                           cntA, inv0, inv1);
  k_scan1<<<NBLK2,256,0,stream>>>(cntA, exclA, bsumA);
  k_scan23<<<NBLK2,256,0,stream>>>(exclA, bsumA, rowA, curA);
  k_scatter_geoA<<<cdiv(ETOT,256),256,0,stream>>>(src0, dst0, src1, dst1, src2, dst2,
                                                  pos0, fp1, fp2, cl1, cl2,
                                                  wr1 + 9*16, wr2 + 9*16,
                                                  curA, slotsA, metaA, rb9);

  const float invsc = 1.f / sqrtf(96.f);
  const int C = 32;

  // pair driver: T_even(mode), attn_even+T_odd, attn_odd
  auto pair32 = [&](const float* xin, const int* rowC, const float* up, const int* inv,
                    int mode, int n, int nodeBase, int Cin,
                    const float* WqE, const float* WkE, const float* WvE, const float* WsE,
                    const float* WqO, const float* WkO, const float* WvO, const float* WsO,
                    int lE, float* xout){
    k_transformF<<<cdiv(n,8),256,0,stream>>>(xin, rowC, slotsA, up, inv,
                                             WqE, WkE, WvE, WsE,
                                             qb, kvb, sb, n, Cin, mode);
    k_attn32_t32<<<cdiv(n,8),256,0,stream>>>(qb, kvb, sb, rowA + nodeBase, slotsA, metaA,
                                             wr1 + lE*16, wr2 + lE*16,
                                             scale_mid + lE*C, bias_mid + lE*C,
                                             WqO, WkO, WvO, WsO, kvb2, n, invsc);
    k_attn32<<<cdiv(n,8),256,0,stream>>>(qb, kvb2, sb, rowA + nodeBase, slotsA, metaA,
                                         wr1 + (lE+1)*16, wr2 + (lE+1)*16,
                                         scale_mid + (lE+1)*C, bias_mid + (lE+1)*C,
                                         xout, n, invsc);
  };

  // pair (0,1) level 0 -> x0s
  pair32(v0, nullptr, nullptr, nullptr, 0, N0, 0, 1,
         Wq_first, Wk_first, Wv_first, Ws_first,
         Wq_mid+0*1024, Wk_mid+0*1024, Wv_mid+0*1024, Ws_mid+0*1024,
         0, x0s);
  // pair (2,3) level 1 (POOL input via cluster1 CSR over x0s) -> x1s
  pair32(x0s, rowA + NTOT, nullptr, nullptr, 1, N1, N0, C,
         Wq_mid+1*1024, Wk_mid+1*1024, Wv_mid+1*1024, Ws_mid+1*1024,
         Wq_mid+2*1024, Wk_mid+2*1024, Wv_mid+2*1024, Ws_mid+2*1024,
         2, x1s);
  // pair (4,5) level 2 (POOL input via cluster2 CSR over x1s) -> xA (N2 rows)
  pair32(x1s, rowA + NTOT + N1, nullptr, nullptr, 1, N2, N0+N1, C,
         Wq_mid+3*1024, Wk_mid+3*1024, Wv_mid+3*1024, Ws_mid+3*1024,
         Wq_mid+4*1024, Wk_mid+4*1024, Wv_mid+4*1024, Ws_mid+4*1024,
         4, xA);
  // pair (6,7) level 1 (UPS input: x1s + xA[inv1]) -> xA (N1 rows)
  pair32(x1s, nullptr, xA, inv1, 2, N1, N0, C,
         Wq_mid+5*1024, Wk_mid+5*1024, Wv_mid+5*1024, Ws_mid+5*1024,
         Wq_mid+6*1024, Wk_mid+6*1024, Wv_mid+6*1024, Ws_mid+6*1024,
         6, xA);
  // pair (8,9): T8 (UPS input: x0s + xA[inv0]), attn8+T9(Cout=1), attn9+head
  k_transformF<<<cdiv(N0,8),256,0,stream>>>(x0s, nullptr, slotsA, xA, inv0,
                                            Wq_mid+7*1024, Wk_mid+7*1024,
                                            Wv_mid+7*1024, Ws_mid+7*1024,
                                            qb, kvb, sb, N0, C, 2);
  k_attn32_t1<<<cdiv(N0,8),256,0,stream>>>(qb, kvb, sb, rowA, slotsA, metaA,
                                           wr1 + 8*16, wr2 + 8*16,
                                           scale_mid + 8*C, bias_mid + 8*C,
                                           Wq_last, Wk_last, Wv_last, Ws_last,
                                           q1v, kv1, s1v, N0, invsc);
  {
    float invsc1 = 1.f / sqrtf(3.f);
    k_attn1_head<<<cdiv(N0,32),256,0,stream>>>(q1v, kv1, s1v, rb9, rowA, slotsA, metaA,
                                               scale_last, bias_last,
                                               Wmlp, (float*)d_out, N0, invsc1);
  }
}